// Round 1
// 388.585 us; speedup vs baseline: 1.0495x; 1.0495x over previous
//
#include <hip/hip_runtime.h>
#include <hip/hip_bf16.h>
#include <math.h>

#define H_HEADS 4
#define D_HEAD 512
#define HD 2048
#define IN_DIM 256
#define OUTD 512
#define NEG 0.2f

typedef __hip_bfloat16 bf16;
typedef _Float16 f16;
typedef __attribute__((ext_vector_type(2))) _Float16 h2v;  // packed fp16 pair
typedef __attribute__((ext_vector_type(8))) short s16x8;   // 8 x bf16 (4 VGPRs)
typedef __attribute__((ext_vector_type(4))) float f32x4;   // MFMA accumulator

__device__ __forceinline__ float bflo(unsigned w) { union { unsigned u; float f; } x; x.u = w << 16; return x.f; }
__device__ __forceinline__ float bfhi(unsigned w) { union { unsigned u; float f; } x; x.u = w & 0xffff0000u; return x.f; }

// ---------------- batched MFMA bf16 GEMM ----------------
// C_z[row, col] = sum_k A_z[row, k] * Bt_z[col, k]
// MODE 0: bf16 output, + bias[col].
// MODE 1: fp32 output, fused: lrelu(acc + bias[col] + (deg(row)>0 ? bias2[col] : 0)).
// MODE 2: f16 output, + bias[col].
// Tile 128x128, BK=32; staging rows clamped to M-1 (never stored OOB).
// LDS bank-conflict fix: chunk index XOR-swizzled by (row>>1)&3 on both the
// staging global-source side and the fragment-read side.
// 16-bit epilogue is SINGLE-PHASE: all 4 waves write their 64x64 quadrant into
// a full 128x136 LDS buffer (34.8 KB), one barrier, then 8 coalesced store
// iterations. (Old 2-phase version idled half the waves and cost 4 barriers.)
template<int MODE>
__global__ __launch_bounds__(256)
void mfma_gemm_kernel(const bf16* __restrict__ A, int lda, long aOff,
                      const bf16* __restrict__ Bt, int ldb, long bOff,
                      const float* __restrict__ bias, long biasOff,
                      const float* __restrict__ bias2, const int* __restrict__ rowptr,
                      void* __restrict__ Cv, int ldc, long cOff,
                      int M, int K)
{
    constexpr int SMEM_BYTES = (MODE == 1) ? (64 * 132 * 4) : (128 * 136 * 2);
    __shared__ __align__(16) char smem_raw[SMEM_BYTES];
    bf16* As = (bf16*)smem_raw;
    bf16* Bs = As + 4096;

    const int tid  = threadIdx.x;
    const int r0   = blockIdx.y * 128;
    const int n0   = blockIdx.x * 128;
    const int z    = blockIdx.z;
    const int lane = tid & 63;
    const int wave = tid >> 6;
    const int wr   = (wave >> 1) * 64;
    const int wc   = (wave & 1) * 64;
    const int l15  = lane & 15;
    const int quad = lane >> 4;

    const bf16* Az = A + aOff * (long)z;
    const bf16* Bz = Bt + bOff * (long)z;

    f32x4 acc[4][4];
    #pragma unroll
    for (int i = 0; i < 4; i++)
        #pragma unroll
        for (int j = 0; j < 4; j++)
            #pragma unroll
            for (int r = 0; r < 4; r++) acc[i][j][r] = 0.f;

    const int srow = tid >> 2;
    // XOR-swizzle: this lane fetches global chunk (k8 ^ key(row)); same 64B window.
    const int skof = (((tid & 3) ^ ((srow >> 1) & 3)) * 8);
    const int swz  = (l15 >> 1) & 3;   // reader-side key: row&15 == l15

    for (int k0 = 0; k0 < K; k0 += 32) {
        #pragma unroll
        for (int p = 0; p < 2; p++) {
            int ar = r0 + p * 64 + srow;
            if (ar >= M) ar = M - 1;
            const bf16* ga = Az + (size_t)ar * lda + k0 + skof;
            __builtin_amdgcn_global_load_lds(
                (const __attribute__((address_space(1))) void*)ga,
                (__attribute__((address_space(3))) void*)(As + (p * 256 + tid) * 8),
                16, 0, 0);
            const bf16* gb = Bz + (size_t)(n0 + p * 64 + srow) * ldb + k0 + skof;
            __builtin_amdgcn_global_load_lds(
                (const __attribute__((address_space(1))) void*)gb,
                (__attribute__((address_space(3))) void*)(Bs + (p * 256 + tid) * 8),
                16, 0, 0);
        }
        __syncthreads();

        s16x8 af[4], bg[4];
        #pragma unroll
        for (int i = 0; i < 4; i++)
            af[i] = *(const s16x8*)(As + (wr + i * 16 + l15) * 32 + (quad ^ swz) * 8);
        #pragma unroll
        for (int j = 0; j < 4; j++)
            bg[j] = *(const s16x8*)(Bs + (wc + j * 16 + l15) * 32 + (quad ^ swz) * 8);
        #pragma unroll
        for (int i = 0; i < 4; i++)
            #pragma unroll
            for (int j = 0; j < 4; j++)
                acc[i][j] = __builtin_amdgcn_mfma_f32_16x16x32_bf16(af[i], bg[j], acc[i][j], 0, 0, 0);
        __syncthreads();
    }

    // C/D frag layout: col = lane&15, row = quad*4 + reg (m89/m91 verified)
    if (MODE == 0 || MODE == 2) {
        float bv[4];
        #pragma unroll
        for (int j = 0; j < 4; j++)
            bv[j] = bias ? bias[biasOff * (long)z + n0 + wc + j * 16 + l15] : 0.f;

        const long cb = cOff * (long)z;

        // single-phase transpose: every wave writes its own quadrant
        if (MODE == 0) {
            bf16* Cs = (bf16*)smem_raw;
            #pragma unroll
            for (int i = 0; i < 4; i++)
                #pragma unroll
                for (int j = 0; j < 4; j++)
                    #pragma unroll
                    for (int r = 0; r < 4; r++)
                        Cs[(wr + i * 16 + quad * 4 + r) * 136 + wc + j * 16 + l15] =
                            __float2bfloat16(acc[i][j][r] + bv[j]);
        } else {
            f16* Cs = (f16*)smem_raw;
            #pragma unroll
            for (int i = 0; i < 4; i++)
                #pragma unroll
                for (int j = 0; j < 4; j++)
                    #pragma unroll
                    for (int r = 0; r < 4; r++)
                        Cs[(wr + i * 16 + quad * 4 + r) * 136 + wc + j * 16 + l15] =
                            (f16)(acc[i][j][r] + bv[j]);
        }
        __syncthreads();
        #pragma unroll
        for (int it = 0; it < 8; it++) {
            const int idx  = it * 256 + tid;
            const int lrow = idx >> 4;
            const int lcol = (idx & 15) * 8;
            const int grow = r0 + lrow;
            if (grow < M)
                *(uint4*)((short*)Cv + cb + (size_t)grow * ldc + n0 + lcol) =
                    *(const uint4*)((const short*)smem_raw + lrow * 136 + lcol);
        }
    } else {
        float* C = (float*)Cv;
        float* Csf = (float*)smem_raw;     // 64 x 132 (padded)

        #pragma unroll
        for (int p = 0; p < 2; p++) {
            __syncthreads();
            if (wr == p * 64) {
                #pragma unroll
                for (int i = 0; i < 4; i++)
                    #pragma unroll
                    for (int j = 0; j < 4; j++)
                        #pragma unroll
                        for (int r = 0; r < 4; r++)
                            Csf[(i * 16 + quad * 4 + r) * 132 + wc + j * 16 + l15] = acc[i][j][r];
            }
            __syncthreads();
            #pragma unroll
            for (int it = 0; it < 8; it++) {
                const int idx  = it * 256 + tid;
                const int lrow = idx >> 5;
                const int lcol = (idx & 31) * 4;
                const int grow = r0 + p * 64 + lrow;
                if (grow < M) {
                    const int gcol = n0 + lcol;
                    float4 v  = *(const float4*)(Csf + lrow * 132 + lcol);
                    const float4 c4 = *(const float4*)(bias + gcol);
                    const float4 b4 = *(const float4*)(bias2 + gcol);
                    const bool has = rowptr[grow + 1] > rowptr[grow];
                    v.x += c4.x + (has ? b4.x : 0.f);
                    v.y += c4.y + (has ? b4.y : 0.f);
                    v.z += c4.z + (has ? b4.z : 0.f);
                    v.w += c4.w + (has ? b4.w : 0.f);
                    v.x = v.x > 0.f ? v.x : NEG * v.x;
                    v.y = v.y > 0.f ? v.y : NEG * v.y;
                    v.z = v.z > 0.f ? v.z : NEG * v.z;
                    v.w = v.w > 0.f ? v.w : NEG * v.w;
                    *(float4*)(C + (size_t)grow * ldc + gcol) = v;
                }
            }
        }
    }
}

// ---------------- prep: casts / transposes / bias concat / attn-f16 (merged) ----------------
__global__ void prep_kernel(const float* __restrict__ W_src, const float* __restrict__ W_dst,
                            const float* __restrict__ W_fc, const float* __restrict__ b_src,
                            const float* __restrict__ b_dst, const float* __restrict__ attn,
                            bf16* __restrict__ WsbT, bf16* __restrict__ WdbT,
                            bf16* __restrict__ WfcT, bf16* __restrict__ Wsb,
                            float* __restrict__ bias_cat, f16* __restrict__ atn16)
{
    int idx = blockIdx.x * 256 + threadIdx.x;
    if (idx < 524288) {
        const int n = idx >> 8, k = idx & 255;
        WsbT[idx] = __float2bfloat16(W_src[(size_t)k * HD + n]);
        return;
    }
    idx -= 524288;
    if (idx < 524288) {
        const int n = idx >> 8, k = idx & 255;
        WdbT[idx] = __float2bfloat16(W_dst[(size_t)k * HD + n]);
        return;
    }
    idx -= 524288;
    if (idx < 1048576) {
        const int n = idx >> 9, t = idx & 511;      // n = h*512 + j
        const int h = n >> 9, j = n & 511;
        WfcT[idx] = __float2bfloat16(W_fc[(size_t)(h * 512 + t) * OUTD + j]);
        return;
    }
    idx -= 1048576;
    if (idx < 524288) {
        Wsb[idx] = __float2bfloat16(W_src[idx]);
        return;
    }
    idx -= 524288;
    if (idx < 2 * HD) {
        bias_cat[idx] = (idx < HD) ? b_src[idx] : b_dst[idx - HD];
        return;
    }
    idx -= 2 * HD;
    if (idx < HD)
        atn16[idx] = (f16)attn[idx];
}

__global__ void cast_bf16_kernel(const float* __restrict__ S, bf16* __restrict__ T, long n4)
{
    const long i = ((long)blockIdx.x * 256 + threadIdx.x) * 4;
    if (i >= n4) return;
    const float4 v = *(const float4*)(S + i);
    T[i + 0] = __float2bfloat16(v.x);
    T[i + 1] = __float2bfloat16(v.y);
    T[i + 2] = __float2bfloat16(v.z);
    T[i + 3] = __float2bfloat16(v.w);
}

// blocks [0,512): cvec[j] = gat_bias @ W_fc[:,j] + b_fc[j]
// blocks [512,1024): bsW_tot[j] = b_src(2048) @ W_fc[:,j]
__global__ __launch_bounds__(256)
void precompute_block_kernel(const float* __restrict__ W_fc, const float* __restrict__ b_fc,
                             const float* __restrict__ gat_bias, const float* __restrict__ b_src,
                             float* __restrict__ cvec, float* __restrict__ bsW_tot)
{
    __shared__ float red[256];
    const int t = threadIdx.x;
    const bool isCvec = blockIdx.x < OUTD;
    const int j = isCvec ? blockIdx.x : blockIdx.x - OUTD;
    const float* vec = isCvec ? gat_bias : b_src;
    float s = 0.f;
    for (int k = t; k < HD; k += 256)
        s = fmaf(vec[k], W_fc[(size_t)k * OUTD + j], s);
    red[t] = s;
    __syncthreads();
    for (int o = 128; o > 0; o >>= 1) {
        if (t < o) red[t] += red[t + o];
        __syncthreads();
    }
    if (t == 0) {
        if (isCvec) cvec[j] = red[0] + b_fc[j];
        else bsW_tot[j] = red[0];
    }
}

__global__ void zero_int_kernel(int* __restrict__ p, int n)
{
    const int i = blockIdx.x * 256 + threadIdx.x;
    if (i < n) p[i] = 0;
}

// ---------------- CSR build ----------------
__global__ void hist_kernel(const int* __restrict__ dst, int* __restrict__ cnt, int E)
{
    const int e = blockIdx.x * 256 + threadIdx.x;
    if (e < E) atomicAdd(&cnt[dst[e]], 1);
}

// single-workgroup scan, shfl-based wave scans (4 barriers/chunk vs 21 for the
// old LDS log-step scan). Also emits cursor[] (= rowptr) directly, removing
// the copy launch.
__global__ __launch_bounds__(1024)
void scan_kernel(const int* __restrict__ cnt, int* __restrict__ rowptr,
                 int* __restrict__ cursor, int n)
{
    __shared__ int wsum[16];
    __shared__ int carry_s;
    const int tid  = threadIdx.x;
    const int lane = tid & 63;
    const int wv   = tid >> 6;
    if (tid == 0) { carry_s = 0; rowptr[0] = 0; cursor[0] = 0; }
    __syncthreads();
    for (int base = 0; base < n; base += 1024) {
        const int i = base + tid;
        int v = (i < n) ? cnt[i] : 0;
        #pragma unroll
        for (int d = 1; d < 64; d <<= 1) {
            const int t = __shfl_up(v, d, 64);
            if (lane >= d) v += t;
        }
        if (lane == 63) wsum[wv] = v;
        __syncthreads();
        if (tid < 16) {
            int w = wsum[tid];
            #pragma unroll
            for (int d = 1; d < 16; d <<= 1) {
                const int t = __shfl_up(w, d, 64);
                if (tid >= d) w += t;
            }
            wsum[tid] = w;
        }
        __syncthreads();
        const int incl = v + (wv ? wsum[wv - 1] : 0) + carry_s;
        if (i < n) {
            rowptr[i + 1] = incl;
            if (i + 1 < n) cursor[i + 1] = incl;
        }
        __syncthreads();                 // all reads of carry_s / wsum done
        if (tid == 1023) carry_s += wsum[15];
        __syncthreads();                 // carry_s/wsum safe for next chunk
    }
}

__global__ void scatter_kernel(const int* __restrict__ src, const int* __restrict__ dst,
                               int* __restrict__ cursor, int* __restrict__ csr_src, int E)
{
    const int e = blockIdx.x * 256 + threadIdx.x;
    if (e >= E) return;
    const int pos = atomicAdd(&cursor[dst[e]], 1);
    csr_src[pos] = src[e];
}

// ---------------- edge scores: packed-f16 math, wave-per-node, 2-edge ILP ----------------
// LeakyReLU(s, 0.2) == 0.6*s + 0.4*|s|, branch-free; |s| via sign-bit mask on
// the packed word. All ops compile to v_pk_{add,mul,fma}_f16.
__device__ __forceinline__ float score_head_h2(const uint4 pa, const uint4 pb, const uint4 at)
{
    const unsigned* ua = (const unsigned*)&pa;
    const unsigned* ub = (const unsigned*)&pb;
    const unsigned* ut = (const unsigned*)&at;
    h2v acc = (h2v)(_Float16)0.f;
    const h2v c06 = (h2v)(_Float16)0.6f;
    const h2v c04 = (h2v)(_Float16)0.4f;
    #pragma unroll
    for (int c = 0; c < 4; c++) {
        union { unsigned u; h2v h; } A, B, T, S, Ab;
        A.u = ua[c]; B.u = ub[c]; T.u = ut[c];
        S.h = A.h + B.h;
        Ab.u = S.u & 0x7fff7fffu;
        const h2v l = S.h * c06 + Ab.h * c04;
        acc += l * T.h;
    }
    return (float)acc.x + (float)acc.y;
}

// ---------------- FUSED score + z-space aggregation ----------------
// agg[v, h*256+k] = (sum_e exp(s_eh) * zb[u_e, k]) / (sum_e exp(s_eh))
// Normalization deferred to end of the node loop -> no expbuf/denomB round
// trip and no second per-node CSR pass. Requires agg NOT to overlay fs.
__global__ __launch_bounds__(256)
void score_agg_kernel(const f16* __restrict__ fs, const f16* __restrict__ fd,
                      const bf16* __restrict__ zb,
                      const int* __restrict__ rowptr, const int* __restrict__ csr_src,
                      const f16* __restrict__ atn16, bf16* __restrict__ agg, int N)
{
    const int wave = threadIdx.x >> 6;
    const int lane = threadIdx.x & 63;
    const int wgid = blockIdx.x * 4 + wave;
    const int nw   = gridDim.x * 4;

    uint4 at[H_HEADS];
    #pragma unroll
    for (int h = 0; h < H_HEADS; h++)
        at[h] = *(const uint4*)(atn16 + h * D_HEAD + lane * 8);

    for (int v = wgid; v < N; v += nw) {
        const int off0 = rowptr[v], off1 = rowptr[v + 1];
        float acc[H_HEADS][4];
        #pragma unroll
        for (int h = 0; h < H_HEADS; h++)
            #pragma unroll
            for (int c = 0; c < 4; c++) acc[h][c] = 0.f;

        if (off1 > off0) {
            uint4 fdr[H_HEADS];
            #pragma unroll
            for (int h = 0; h < H_HEADS; h++)
                fdr[h] = *(const uint4*)(fd + (size_t)v * HD + h * D_HEAD + lane * 8);

            float den[H_HEADS] = {0.f, 0.f, 0.f, 0.f};
            for (int o = off0; o < off1; o += 2) {
                const bool two = (o + 1 < off1);
                const int u0 = csr_src[o];
                const int u1 = two ? csr_src[o + 1] : u0;
                const f16* f0 = fs + (size_t)u0 * HD + lane * 8;
                const f16* f1 = fs + (size_t)u1 * HD + lane * 8;
                uint4 pa0[H_HEADS], pa1[H_HEADS];
                #pragma unroll
                for (int h = 0; h < H_HEADS; h++) pa0[h] = *(const uint4*)(f0 + h * D_HEAD);
                #pragma unroll
                for (int h = 0; h < H_HEADS; h++) pa1[h] = *(const uint4*)(f1 + h * D_HEAD);
                const uint2 z0 = *(const uint2*)(zb + (size_t)u0 * IN_DIM + lane * 4);
                const uint2 z1 = *(const uint2*)(zb + (size_t)u1 * IN_DIM + lane * 4);

                float s0[H_HEADS], s1[H_HEADS];
                #pragma unroll
                for (int h = 0; h < H_HEADS; h++) {
                    s0[h] = score_head_h2(pa0[h], fdr[h], at[h]);
                    s1[h] = score_head_h2(pa1[h], fdr[h], at[h]);
                }
                #pragma unroll
                for (int ofs = 32; ofs > 0; ofs >>= 1) {
                    #pragma unroll
                    for (int h = 0; h < H_HEADS; h++) {
                        s0[h] += __shfl_xor(s0[h], ofs, 64);
                        s1[h] += __shfl_xor(s1[h], ofs, 64);
                    }
                }
                // scores O(0.2): max-subtraction safely skipped (cancels in
                // num/den anyway, so deferred normalization is exact)
                float e0[H_HEADS];
                #pragma unroll
                for (int h = 0; h < H_HEADS; h++) e0[h] = expf(s0[h]);
                const float zc0[4] = {bflo(z0.x), bfhi(z0.x), bflo(z0.y), bfhi(z0.y)};
                #pragma unroll
                for (int h = 0; h < H_HEADS; h++) {
                    den[h] += e0[h];
                    #pragma unroll
                    for (int c = 0; c < 4; c++) acc[h][c] = fmaf(e0[h], zc0[c], acc[h][c]);
                }
                if (two) {
                    float e1[H_HEADS];
                    #pragma unroll
                    for (int h = 0; h < H_HEADS; h++) e1[h] = expf(s1[h]);
                    const float zc1[4] = {bflo(z1.x), bfhi(z1.x), bflo(z1.y), bfhi(z1.y)};
                    #pragma unroll
                    for (int h = 0; h < H_HEADS; h++) {
                        den[h] += e1[h];
                        #pragma unroll
                        for (int c = 0; c < 4; c++) acc[h][c] = fmaf(e1[h], zc1[c], acc[h][c]);
                    }
                }
            }
            #pragma unroll
            for (int h = 0; h < H_HEADS; h++) {
                const float inv = 1.f / den[h];
                #pragma unroll
                for (int c = 0; c < 4; c++) acc[h][c] *= inv;
            }
        }
        #pragma unroll
        for (int h = 0; h < H_HEADS; h++) {
            union { uint2 u; short s[4]; } pk;
            #pragma unroll
            for (int c = 0; c < 4; c++) {
                const bf16 b = __float2bfloat16(acc[h][c]);
                pk.s[c] = *(const short*)&b;
            }
            *(uint2*)(agg + (size_t)v * (H_HEADS * IN_DIM) + h * IN_DIM + lane * 4) = pk.u;
        }
    }
}

// ---------------- fallback pair (used only if workspace too small for a
// separate agg buffer; agg then overlays fs, so score/agg must be 2 passes)
__global__ __launch_bounds__(256)
void score_csr_kernel(const f16* __restrict__ fs, const f16* __restrict__ fd,
                      const int* __restrict__ rowptr, const int* __restrict__ csr_src,
                      const f16* __restrict__ atn16, float* __restrict__ expbuf,
                      float* __restrict__ denomB, int N)
{
    const int wave = threadIdx.x >> 6;
    const int lane = threadIdx.x & 63;
    const int wgid = blockIdx.x * 4 + wave;
    const int nw   = gridDim.x * 4;

    uint4 at[H_HEADS];
    #pragma unroll
    for (int h = 0; h < H_HEADS; h++)
        at[h] = *(const uint4*)(atn16 + h * D_HEAD + lane * 8);

    for (int v = wgid; v < N; v += nw) {
        const int off0 = rowptr[v], off1 = rowptr[v + 1];
        if (off0 == off1) continue;
        uint4 fdr[H_HEADS];
        #pragma unroll
        for (int h = 0; h < H_HEADS; h++)
            fdr[h] = *(const uint4*)(fd + (size_t)v * HD + h * D_HEAD + lane * 8);

        float4 den = make_float4(0.f, 0.f, 0.f, 0.f);
        for (int o = off0; o < off1; o += 2) {
            const bool two = (o + 1 < off1);
            const int u0 = csr_src[o];
            const int u1 = two ? csr_src[o + 1] : u0;
            const f16* f0 = fs + (size_t)u0 * HD + lane * 8;
            const f16* f1 = fs + (size_t)u1 * HD + lane * 8;
            uint4 pa0[H_HEADS], pa1[H_HEADS];
            #pragma unroll
            for (int h = 0; h < H_HEADS; h++) pa0[h] = *(const uint4*)(f0 + h * D_HEAD);
            #pragma unroll
            for (int h = 0; h < H_HEADS; h++) pa1[h] = *(const uint4*)(f1 + h * D_HEAD);

            float s0[H_HEADS], s1[H_HEADS];
            #pragma unroll
            for (int h = 0; h < H_HEADS; h++) {
                s0[h] = score_head_h2(pa0[h], fdr[h], at[h]);
                s1[h] = score_head_h2(pa1[h], fdr[h], at[h]);
            }
            #pragma unroll
            for (int ofs = 32; ofs > 0; ofs >>= 1) {
                #pragma unroll
                for (int h = 0; h < H_HEADS; h++) {
                    s0[h] += __shfl_xor(s0[h], ofs, 64);
                    s1[h] += __shfl_xor(s1[h], ofs, 64);
                }
            }
            const float4 e0 = make_float4(expf(s0[0]), expf(s0[1]), expf(s0[2]), expf(s0[3]));
            den.x += e0.x; den.y += e0.y; den.z += e0.z; den.w += e0.w;
            float4 e1;
            if (two) {
                e1 = make_float4(expf(s1[0]), expf(s1[1]), expf(s1[2]), expf(s1[3]));
                den.x += e1.x; den.y += e1.y; den.z += e1.z; den.w += e1.w;
            }
            if (lane == 0) {
                *(float4*)(expbuf + (size_t)o * H_HEADS) = e0;
                if (two) *(float4*)(expbuf + (size_t)(o + 1) * H_HEADS) = e1;
            }
        }
        if (lane == 0) *(float4*)(denomB + (size_t)v * H_HEADS) = den;
    }
}

__global__ __launch_bounds__(256)
void agg_z_kernel(const bf16* __restrict__ zb, const int* __restrict__ rowptr,
                  const int* __restrict__ csr_src, const float* __restrict__ expbuf,
                  const float* __restrict__ denomB, bf16* __restrict__ agg, int N)
{
    const int wave = threadIdx.x >> 6;
    const int lane = threadIdx.x & 63;
    const int wgid = blockIdx.x * 4 + wave;
    const int nw   = gridDim.x * 4;

    for (int v = wgid; v < N; v += nw) {
        const int off0 = rowptr[v], off1 = rowptr[v + 1];
        float acc[H_HEADS][4];
        #pragma unroll
        for (int h = 0; h < H_HEADS; h++)
            #pragma unroll
            for (int c = 0; c < 4; c++) acc[h][c] = 0.f;

        if (off1 > off0) {
            const float4 den = *(const float4*)(denomB + (size_t)v * H_HEADS);
            const float4 inv = make_float4(1.f / den.x, 1.f / den.y, 1.f / den.z, 1.f / den.w);
            int o = off0;
            for (; o + 1 < off1; o += 2) {
                const float4 e0 = *(const float4*)(expbuf + (size_t)o * H_HEADS);
                const float4 e1 = *(const float4*)(expbuf + (size_t)(o + 1) * H_HEADS);
                const int u0 = csr_src[o], u1 = csr_src[o + 1];
                const uint2 z0 = *(const uint2*)(zb + (size_t)u0 * IN_DIM + lane * 4);
                const uint2 z1 = *(const uint2*)(zb + (size_t)u1 * IN_DIM + lane * 4);
                const float a0[4] = {e0.x * inv.x, e0.y * inv.y, e0.z * inv.z, e0.w * inv.w};
                const float a1[4] = {e1.x * inv.x, e1.y * inv.y, e1.z * inv.z, e1.w * inv.w};
                const float zc0[4] = {bflo(z0.x), bfhi(z0.x), bflo(z0.y), bfhi(z0.y)};
                const float zc1[4] = {bflo(z1.x), bfhi(z1.x), bflo(z1.y), bfhi(z1.y)};
                #pragma unroll
                for (int h = 0; h < H_HEADS; h++)
                    #pragma unroll
                    for (int c = 0; c < 4; c++)
                        acc[h][c] += a0[h] * zc0[c] + a1[h] * zc1[c];
            }
            if (o < off1) {
                const float4 e0 = *(const float4*)(expbuf + (size_t)o * H_HEADS);
                const float4 den2 = *(const float4*)(denomB + (size_t)v * H_HEADS);
                const float4 inv2 = make_float4(1.f / den2.x, 1.f / den2.y, 1.f / den2.z, 1.f / den2.w);
                const int u0 = csr_src[o];
                const uint2 z0 = *(const uint2*)(zb + (size_t)u0 * IN_DIM + lane * 4);
                const float a0[4] = {e0.x * inv2.x, e0.y * inv2.y, e0.z * inv2.z, e0.w * inv2.w};
                const float zc0[4] = {bflo(z0.x), bfhi(z0.x), bflo(z0.y), bfhi(z0.y)};
                #pragma unroll
                for (int h = 0; h < H_HEADS; h++)
                    #pragma unroll
                    for (int c = 0; c < 4; c++)
                        acc[h][c] += a0[h] * zc0[c];
            }
        }
        #pragma unroll
        for (int h = 0; h < H_HEADS; h++) {
            union { uint2 u; short s[4]; } pk;
            #pragma unroll
            for (int c = 0; c < 4; c++) {
                const bf16 b = __float2bfloat16(acc[h][c]);
                pk.s[c] = *(const short*)&b;
            }
            *(uint2*)(agg + (size_t)v * (H_HEADS * IN_DIM) + h * IN_DIM + lane * 4) = pk.u;
        }
    }
}

extern "C" void kernel_launch(void* const* d_in, const int* in_sizes, int n_in,
                              void* d_out, int out_size, void* d_ws, size_t ws_size,
                              hipStream_t stream)
{
    const float* z        = (const float*)d_in[0];
    const int*   src      = (const int*)d_in[1];
    const int*   dst      = (const int*)d_in[2];
    const float* W_src    = (const float*)d_in[3];
    const float* b_src    = (const float*)d_in[4];
    const float* W_dst    = (const float*)d_in[5];
    const float* b_dst    = (const float*)d_in[6];
    const float* attn     = (const float*)d_in[7];
    const float* gat_bias = (const float*)d_in[8];
    const float* W_fc     = (const float*)d_in[9];
    const float* b_fc     = (const float*)d_in[10];
    float* out = (float*)d_out;

    const int N = in_sizes[0] / IN_DIM;   // 20000
    const int E = in_sizes[1];            // 100000

    // Workspace (~184 MB base; +41 MB for separate agg if ws_size allows).
    char* p = (char*)d_ws;
    const size_t featB = (size_t)N * HD * 2;
    f16* fs       = (f16*)p;   p += featB;                               // 81.92 MB (f16)
    f16* fd       = (f16*)p;   p += featB;                               // 81.92 MB (f16)
    bf16* zb      = (bf16*)p;  p += (size_t)N * IN_DIM * sizeof(bf16);   // 10.24 MB
    bf16* WsbT    = (bf16*)p;  p += (size_t)HD * IN_DIM * sizeof(bf16);  // 1.05 MB
    bf16* WdbT    = (bf16*)p;  p += (size_t)HD * IN_DIM * sizeof(bf16);  // 1.05 MB
    bf16* Wsb     = (bf16*)p;  p += (size_t)IN_DIM * HD * sizeof(bf16);  // 1.05 MB
    bf16* WfcT    = (bf16*)p;  p += (size_t)HD * D_HEAD * sizeof(bf16);  // 2.10 MB
    bf16* Wfinal  = (bf16*)p;  p += (size_t)OUTD * 1024 * sizeof(bf16);  // 1.05 MB
    float* bias_cat = (float*)p; p += (size_t)2 * HD * sizeof(float);    // 16 KB
    f16* atn16    = (f16*)p;   p += (size_t)HD * sizeof(f16);            // 4 KB
    float* bsW_tot = (float*)p; p += (size_t)OUTD * sizeof(float);
    float* cvec   = (float*)p; p += (size_t)OUTD * sizeof(float);
    float* expbuf = (float*)p; p += (size_t)E * H_HEADS * sizeof(float); // 1.6 MB
    float* denomB = (float*)p; p += (size_t)N * H_HEADS * sizeof(float); // 0.32 MB
    int* cnt      = (int*)p;   p += ((size_t)N * 4 + 15) & ~15ULL;
    int* rowptr   = (int*)p;   p += ((size_t)(N + 1) * 4 + 15) & ~15ULL;
    int* cursor   = (int*)p;   p += ((size_t)N * 4 + 15) & ~15ULL;
    int* csr_src  = (int*)p;   p += ((size_t)E * 4 + 15) & ~15ULL;

    // Separate agg buffer (fused score+agg needs fs live while writing agg);
    // fall back to overlaying fs + 2-pass kernels if workspace is too small.
    bf16* aggSep = (bf16*)p;
    const size_t needFused = (size_t)(p - (char*)d_ws) + (size_t)N * (H_HEADS * IN_DIM) * sizeof(bf16);
    const bool fused = (ws_size >= needFused);
    bf16* agg = fused ? aggSep : (bf16*)fs;

    // Prep: weight casts/transposes + bias concat + attn f16, z cast, cvec/bsW_tot.
    const int prepElems = 524288 * 3 + 1048576 + 2 * HD + HD;
    prep_kernel<<<(prepElems + 255) / 256, 256, 0, stream>>>(
        W_src, W_dst, W_fc, b_src, b_dst, attn, WsbT, WdbT, WfcT, Wsb, bias_cat, atn16);
    cast_bf16_kernel<<<((long)N * IN_DIM / 4 + 255) / 256, 256, 0, stream>>>(z, zb, (long)N * IN_DIM);
    precompute_block_kernel<<<2 * OUTD, 256, 0, stream>>>(W_fc, b_fc, gat_bias, b_src, cvec, bsW_tot);

    // CSR build (scan also emits cursor)
    zero_int_kernel<<<(N + 255) / 256, 256, 0, stream>>>(cnt, N);
    hist_kernel<<<(E + 255) / 256, 256, 0, stream>>>(dst, cnt, E);
    scan_kernel<<<1, 1024, 0, stream>>>(cnt, rowptr, cursor, N);
    scatter_kernel<<<(E + 255) / 256, 256, 0, stream>>>(src, dst, cursor, csr_src, E);

    // Wfinal[j, h*256+k] = Wcomb_h[k, j]
    mfma_gemm_kernel<0><<<dim3(IN_DIM / 128, D_HEAD / 128, H_HEADS), 256, 0, stream>>>(
        WfcT, D_HEAD, (long)D_HEAD * D_HEAD,
        Wsb, HD, (long)D_HEAD,
        nullptr, 0, nullptr, nullptr,
        Wfinal, 1024, (long)IN_DIM,
        D_HEAD, D_HEAD);

    // fs,fd = zb @ {W_src,W_dst} + {b_src,b_dst}, f16 output (one z=2 dispatch)
    mfma_gemm_kernel<2><<<dim3(HD / 128, (N + 127) / 128, 2), 256, 0, stream>>>(
        zb, IN_DIM, 0L,
        WsbT, IN_DIM, (long)HD * IN_DIM,
        bias_cat, (long)HD, nullptr, nullptr,
        fs, HD, (long)N * HD,
        N, IN_DIM);

    // Edge scores + z-space aggregation
    if (fused) {
        score_agg_kernel<<<2500, 256, 0, stream>>>(fs, fd, zb, rowptr, csr_src, atn16, agg, N);
    } else {
        score_csr_kernel<<<2500, 256, 0, stream>>>(fs, fd, rowptr, csr_src, atn16, expbuf, denomB, N);
        agg_z_kernel<<<2500, 256, 0, stream>>>(zb, rowptr, csr_src, expbuf, denomB, agg, N);
    }

    // out = lrelu(agg @ Wfinal^T + cvec + deg?bsW_tot), fused epilogue
    mfma_gemm_kernel<1><<<dim3(OUTD / 128, (N + 127) / 128, 1), 256, 0, stream>>>(
        agg, H_HEADS * IN_DIM, 0L,
        Wfinal, H_HEADS * IN_DIM, 0L,
        cvec, 0L, bsW_tot, rowptr,
        out, OUTD, 0L,
        N, H_HEADS * IN_DIM);
}

// Round 2
// 377.423 us; speedup vs baseline: 1.0805x; 1.0296x over previous
//
#include <hip/hip_runtime.h>
#include <hip/hip_bf16.h>
#include <math.h>

#define H_HEADS 4
#define D_HEAD 512
#define HD 2048
#define IN_DIM 256
#define OUTD 512
#define NEG 0.2f

typedef __hip_bfloat16 bf16;
typedef _Float16 f16;
typedef __attribute__((ext_vector_type(2))) _Float16 h2v;  // packed fp16 pair
typedef __attribute__((ext_vector_type(8))) short s16x8;   // 8 x bf16 (4 VGPRs)
typedef __attribute__((ext_vector_type(4))) float f32x4;   // MFMA accumulator

__device__ __forceinline__ float bflo(unsigned w) { union { unsigned u; float f; } x; x.u = w << 16; return x.f; }
__device__ __forceinline__ float bfhi(unsigned w) { union { unsigned u; float f; } x; x.u = w & 0xffff0000u; return x.f; }

// ---------------- batched MFMA bf16 GEMM ----------------
// C_z[row, col] = sum_k A_z[row, k] * Bt_z[col, k]
// MODE 0: bf16 output, + bias[col].
// MODE 1: fp32 output, fused: lrelu(acc + bias[col] + (deg(row)>0 ? bias2[col] : 0)).
// MODE 2: f16 output, + bias[col].
// Tile 128x128, BK=32; staging rows clamped to M-1 (never stored OOB).
// LDS bank-conflict fix: chunk index XOR-swizzled by (row>>1)&3 on both the
// staging global-source side and the fragment-read side.
// 16-bit epilogue is SINGLE-PHASE: all 4 waves write their 64x64 quadrant into
// a full 128x136 LDS buffer (34.8 KB), one barrier, then 8 coalesced store
// iterations.
template<int MODE>
__global__ __launch_bounds__(256)
void mfma_gemm_kernel(const bf16* __restrict__ A, int lda, long aOff,
                      const bf16* __restrict__ Bt, int ldb, long bOff,
                      const float* __restrict__ bias, long biasOff,
                      const float* __restrict__ bias2, const int* __restrict__ rowptr,
                      void* __restrict__ Cv, int ldc, long cOff,
                      int M, int K)
{
    constexpr int SMEM_BYTES = (MODE == 1) ? (64 * 132 * 4) : (128 * 136 * 2);
    __shared__ __align__(16) char smem_raw[SMEM_BYTES];
    bf16* As = (bf16*)smem_raw;
    bf16* Bs = As + 4096;

    const int tid  = threadIdx.x;
    const int r0   = blockIdx.y * 128;
    const int n0   = blockIdx.x * 128;
    const int z    = blockIdx.z;
    const int lane = tid & 63;
    const int wave = tid >> 6;
    const int wr   = (wave >> 1) * 64;
    const int wc   = (wave & 1) * 64;
    const int l15  = lane & 15;
    const int quad = lane >> 4;

    const bf16* Az = A + aOff * (long)z;
    const bf16* Bz = Bt + bOff * (long)z;

    f32x4 acc[4][4];
    #pragma unroll
    for (int i = 0; i < 4; i++)
        #pragma unroll
        for (int j = 0; j < 4; j++)
            #pragma unroll
            for (int r = 0; r < 4; r++) acc[i][j][r] = 0.f;

    const int srow = tid >> 2;
    // XOR-swizzle: this lane fetches global chunk (k8 ^ key(row)); same 64B window.
    const int skof = (((tid & 3) ^ ((srow >> 1) & 3)) * 8);
    const int swz  = (l15 >> 1) & 3;   // reader-side key: row&15 == l15

    for (int k0 = 0; k0 < K; k0 += 32) {
        #pragma unroll
        for (int p = 0; p < 2; p++) {
            int ar = r0 + p * 64 + srow;
            if (ar >= M) ar = M - 1;
            const bf16* ga = Az + (size_t)ar * lda + k0 + skof;
            __builtin_amdgcn_global_load_lds(
                (const __attribute__((address_space(1))) void*)ga,
                (__attribute__((address_space(3))) void*)(As + (p * 256 + tid) * 8),
                16, 0, 0);
            const bf16* gb = Bz + (size_t)(n0 + p * 64 + srow) * ldb + k0 + skof;
            __builtin_amdgcn_global_load_lds(
                (const __attribute__((address_space(1))) void*)gb,
                (__attribute__((address_space(3))) void*)(Bs + (p * 256 + tid) * 8),
                16, 0, 0);
        }
        __syncthreads();

        s16x8 af[4], bg[4];
        #pragma unroll
        for (int i = 0; i < 4; i++)
            af[i] = *(const s16x8*)(As + (wr + i * 16 + l15) * 32 + (quad ^ swz) * 8);
        #pragma unroll
        for (int j = 0; j < 4; j++)
            bg[j] = *(const s16x8*)(Bs + (wc + j * 16 + l15) * 32 + (quad ^ swz) * 8);
        #pragma unroll
        for (int i = 0; i < 4; i++)
            #pragma unroll
            for (int j = 0; j < 4; j++)
                acc[i][j] = __builtin_amdgcn_mfma_f32_16x16x32_bf16(af[i], bg[j], acc[i][j], 0, 0, 0);
        __syncthreads();
    }

    // C/D frag layout: col = lane&15, row = quad*4 + reg (m89/m91 verified)
    if (MODE == 0 || MODE == 2) {
        float bv[4];
        #pragma unroll
        for (int j = 0; j < 4; j++)
            bv[j] = bias ? bias[biasOff * (long)z + n0 + wc + j * 16 + l15] : 0.f;

        const long cb = cOff * (long)z;

        // single-phase transpose: every wave writes its own quadrant
        if (MODE == 0) {
            bf16* Cs = (bf16*)smem_raw;
            #pragma unroll
            for (int i = 0; i < 4; i++)
                #pragma unroll
                for (int j = 0; j < 4; j++)
                    #pragma unroll
                    for (int r = 0; r < 4; r++)
                        Cs[(wr + i * 16 + quad * 4 + r) * 136 + wc + j * 16 + l15] =
                            __float2bfloat16(acc[i][j][r] + bv[j]);
        } else {
            f16* Cs = (f16*)smem_raw;
            #pragma unroll
            for (int i = 0; i < 4; i++)
                #pragma unroll
                for (int j = 0; j < 4; j++)
                    #pragma unroll
                    for (int r = 0; r < 4; r++)
                        Cs[(wr + i * 16 + quad * 4 + r) * 136 + wc + j * 16 + l15] =
                            (f16)(acc[i][j][r] + bv[j]);
        }
        __syncthreads();
        #pragma unroll
        for (int it = 0; it < 8; it++) {
            const int idx  = it * 256 + tid;
            const int lrow = idx >> 4;
            const int lcol = (idx & 15) * 8;
            const int grow = r0 + lrow;
            if (grow < M)
                *(uint4*)((short*)Cv + cb + (size_t)grow * ldc + n0 + lcol) =
                    *(const uint4*)((const short*)smem_raw + lrow * 136 + lcol);
        }
    } else {
        float* C = (float*)Cv;
        float* Csf = (float*)smem_raw;     // 64 x 132 (padded)

        #pragma unroll
        for (int p = 0; p < 2; p++) {
            __syncthreads();
            if (wr == p * 64) {
                #pragma unroll
                for (int i = 0; i < 4; i++)
                    #pragma unroll
                    for (int j = 0; j < 4; j++)
                        #pragma unroll
                        for (int r = 0; r < 4; r++)
                            Csf[(i * 16 + quad * 4 + r) * 132 + wc + j * 16 + l15] = acc[i][j][r];
            }
            __syncthreads();
            #pragma unroll
            for (int it = 0; it < 8; it++) {
                const int idx  = it * 256 + tid;
                const int lrow = idx >> 5;
                const int lcol = (idx & 31) * 4;
                const int grow = r0 + p * 64 + lrow;
                if (grow < M) {
                    const int gcol = n0 + lcol;
                    float4 v  = *(const float4*)(Csf + lrow * 132 + lcol);
                    const float4 c4 = *(const float4*)(bias + gcol);
                    const float4 b4 = *(const float4*)(bias2 + gcol);
                    const bool has = rowptr[grow + 1] > rowptr[grow];
                    v.x += c4.x + (has ? b4.x : 0.f);
                    v.y += c4.y + (has ? b4.y : 0.f);
                    v.z += c4.z + (has ? b4.z : 0.f);
                    v.w += c4.w + (has ? b4.w : 0.f);
                    v.x = v.x > 0.f ? v.x : NEG * v.x;
                    v.y = v.y > 0.f ? v.y : NEG * v.y;
                    v.z = v.z > 0.f ? v.z : NEG * v.z;
                    v.w = v.w > 0.f ? v.w : NEG * v.w;
                    *(float4*)(C + (size_t)grow * ldc + gcol) = v;
                }
            }
        }
    }
}

// ---------------- prep: casts / transposes / bias concat / attn-f16 / cnt-zero
// plus (extra block range) the two 2048-dot reductions (cvec / bsW_tot) that
// used to be precompute_block_kernel. Role split on blockIdx.
__global__ __launch_bounds__(256)
void prep_kernel(const float* __restrict__ W_src, const float* __restrict__ W_dst,
                 const float* __restrict__ W_fc, const float* __restrict__ b_src,
                 const float* __restrict__ b_dst, const float* __restrict__ attn,
                 const float* __restrict__ b_fc, const float* __restrict__ gat_bias,
                 bf16* __restrict__ WsbT, bf16* __restrict__ WdbT,
                 bf16* __restrict__ WfcT, bf16* __restrict__ Wsb,
                 float* __restrict__ bias_cat, f16* __restrict__ atn16,
                 int* __restrict__ cnt, int nCnt,
                 float* __restrict__ cvec, float* __restrict__ bsW_tot, int prepBlocks)
{
    __shared__ float red[256];
    if ((int)blockIdx.x >= prepBlocks) {
        // reduction role: cvec[j] = gat_bias @ W_fc[:,j] + b_fc[j]  (b < OUTD)
        //                 bsW_tot[j] = b_src @ W_fc[:,j]            (b >= OUTD)
        const int b = blockIdx.x - prepBlocks;
        const int t = threadIdx.x;
        const bool isCvec = b < OUTD;
        const int j = isCvec ? b : b - OUTD;
        const float* vec = isCvec ? gat_bias : b_src;
        float s = 0.f;
        for (int k = t; k < HD; k += 256)
            s = fmaf(vec[k], W_fc[(size_t)k * OUTD + j], s);
        red[t] = s;
        __syncthreads();
        for (int o = 128; o > 0; o >>= 1) {
            if (t < o) red[t] += red[t + o];
            __syncthreads();
        }
        if (t == 0) {
            if (isCvec) cvec[j] = red[0] + b_fc[j];
            else bsW_tot[j] = red[0];
        }
        return;
    }
    int idx = blockIdx.x * 256 + threadIdx.x;
    if (idx < 524288) {
        const int n = idx >> 8, k = idx & 255;
        WsbT[idx] = __float2bfloat16(W_src[(size_t)k * HD + n]);
        return;
    }
    idx -= 524288;
    if (idx < 524288) {
        const int n = idx >> 8, k = idx & 255;
        WdbT[idx] = __float2bfloat16(W_dst[(size_t)k * HD + n]);
        return;
    }
    idx -= 524288;
    if (idx < 1048576) {
        const int n = idx >> 9, t = idx & 511;      // n = h*512 + j
        const int h = n >> 9, j = n & 511;
        WfcT[idx] = __float2bfloat16(W_fc[(size_t)(h * 512 + t) * OUTD + j]);
        return;
    }
    idx -= 1048576;
    if (idx < 524288) {
        Wsb[idx] = __float2bfloat16(W_src[idx]);
        return;
    }
    idx -= 524288;
    if (idx < 2 * HD) {
        bias_cat[idx] = (idx < HD) ? b_src[idx] : b_dst[idx - HD];
        return;
    }
    idx -= 2 * HD;
    if (idx < HD) {
        atn16[idx] = (f16)attn[idx];
        return;
    }
    idx -= HD;
    if (idx < nCnt) cnt[idx] = 0;
}

// cast z -> bf16, plus (tail range) degree histogram (cnt zeroed by prep)
__global__ void cast_hist_kernel(const float* __restrict__ S, bf16* __restrict__ T,
                                 long n4, const int* __restrict__ dst,
                                 int* __restrict__ cnt, int E)
{
    long t = (long)blockIdx.x * 256 + threadIdx.x;
    if (t < n4) {
        const long i = t * 4;
        const float4 v = *(const float4*)(S + i);
        T[i + 0] = __float2bfloat16(v.x);
        T[i + 1] = __float2bfloat16(v.y);
        T[i + 2] = __float2bfloat16(v.z);
        T[i + 3] = __float2bfloat16(v.w);
        return;
    }
    t -= n4;
    if (t < E) atomicAdd(&cnt[dst[t]], 1);
}

// single-workgroup scan, shfl-based wave scans; emits cursor[] (= rowptr) too.
__global__ __launch_bounds__(1024)
void scan_kernel(const int* __restrict__ cnt, int* __restrict__ rowptr,
                 int* __restrict__ cursor, int n)
{
    __shared__ int wsum[16];
    __shared__ int carry_s;
    const int tid  = threadIdx.x;
    const int lane = tid & 63;
    const int wv   = tid >> 6;
    if (tid == 0) { carry_s = 0; rowptr[0] = 0; cursor[0] = 0; }
    __syncthreads();
    for (int base = 0; base < n; base += 1024) {
        const int i = base + tid;
        int v = (i < n) ? cnt[i] : 0;
        #pragma unroll
        for (int d = 1; d < 64; d <<= 1) {
            const int t = __shfl_up(v, d, 64);
            if (lane >= d) v += t;
        }
        if (lane == 63) wsum[wv] = v;
        __syncthreads();
        if (tid < 16) {
            int w = wsum[tid];
            #pragma unroll
            for (int d = 1; d < 16; d <<= 1) {
                const int t = __shfl_up(w, d, 64);
                if (tid >= d) w += t;
            }
            wsum[tid] = w;
        }
        __syncthreads();
        const int incl = v + (wv ? wsum[wv - 1] : 0) + carry_s;
        if (i < n) {
            rowptr[i + 1] = incl;
            if (i + 1 < n) cursor[i + 1] = incl;
        }
        __syncthreads();                 // all reads of carry_s / wsum done
        if (tid == 1023) carry_s += wsum[15];
        __syncthreads();                 // carry_s/wsum safe for next chunk
    }
}

__global__ void scatter_kernel(const int* __restrict__ src, const int* __restrict__ dst,
                               int* __restrict__ cursor, int* __restrict__ csr_src, int E)
{
    const int e = blockIdx.x * 256 + threadIdx.x;
    if (e >= E) return;
    const int pos = atomicAdd(&cursor[dst[e]], 1);
    csr_src[pos] = src[e];
}

// ---------------- edge scores: packed-f16 math ----------------
// LeakyReLU(s, 0.2) == 0.6*s + 0.4*|s|, branch-free; |s| via sign-bit mask on
// the packed word. All ops compile to v_pk_{add,mul,fma}_f16.
__device__ __forceinline__ float score_head_h2(const uint4 pa, const uint4 pb, const uint4 at)
{
    const unsigned* ua = (const unsigned*)&pa;
    const unsigned* ub = (const unsigned*)&pb;
    const unsigned* ut = (const unsigned*)&at;
    h2v acc = (h2v)(_Float16)0.f;
    const h2v c06 = (h2v)(_Float16)0.6f;
    const h2v c04 = (h2v)(_Float16)0.4f;
    #pragma unroll
    for (int c = 0; c < 4; c++) {
        union { unsigned u; h2v h; } A, B, T, S, Ab;
        A.u = ua[c]; B.u = ub[c]; T.u = ut[c];
        S.h = A.h + B.h;
        Ab.u = S.u & 0x7fff7fffu;
        const h2v l = S.h * c06 + Ab.h * c04;
        acc += l * T.h;
    }
    return (float)acc.x + (float)acc.y;
}

// ---------------- FUSED score + z-space aggregation, per-(node,head) ----------------
// block = node, wave = head. Scores and aggregation decompose per head: wave h
// reads only the h-th 512-slice of fs/fd (16B/lane, coalesced 1KB), reduces one
// scalar over 64 lanes (6 shuffles vs 24/edge before), and accumulates the
// 256-dim z-aggregate for its head (acc[4]). The 4 head-waves walk the same
// edge list -> csr_src/zb re-reads are L1 broadcasts, no extra HBM traffic.
// agg[v, h*256+k] = (sum_e exp(s_eh) * zb[u_e, k]) / (sum_e exp(s_eh))
__global__ __launch_bounds__(256)
void score_agg_kernel(const f16* __restrict__ fs, const f16* __restrict__ fd,
                      const bf16* __restrict__ zb,
                      const int* __restrict__ rowptr, const int* __restrict__ csr_src,
                      const f16* __restrict__ atn16, bf16* __restrict__ agg, int N)
{
    const int h    = threadIdx.x >> 6;     // wave index = head
    const int lane = threadIdx.x & 63;
    const int v    = blockIdx.x;
    if (v >= N) return;

    const uint4 at = *(const uint4*)(atn16 + h * D_HEAD + lane * 8);
    const f16* fsh = fs + h * D_HEAD + lane * 8;

    const int off0 = rowptr[v], off1 = rowptr[v + 1];
    float acc[4] = {0.f, 0.f, 0.f, 0.f};

    if (off1 > off0) {
        const uint4 fdr = *(const uint4*)(fd + (size_t)v * HD + h * D_HEAD + lane * 8);
        float den = 0.f;
        for (int o = off0; o < off1; o += 2) {
            const bool two = (o + 1 < off1);
            const int u0 = csr_src[o];
            const int u1 = two ? csr_src[o + 1] : u0;
            const uint4 pa0 = *(const uint4*)(fsh + (size_t)u0 * HD);
            const uint4 pa1 = *(const uint4*)(fsh + (size_t)u1 * HD);
            const uint2 z0 = *(const uint2*)(zb + (size_t)u0 * IN_DIM + lane * 4);
            const uint2 z1 = *(const uint2*)(zb + (size_t)u1 * IN_DIM + lane * 4);

            float s0 = score_head_h2(pa0, fdr, at);
            float s1 = score_head_h2(pa1, fdr, at);
            #pragma unroll
            for (int ofs = 32; ofs > 0; ofs >>= 1) {
                s0 += __shfl_xor(s0, ofs, 64);
                s1 += __shfl_xor(s1, ofs, 64);
            }
            // scores O(0.2): max-subtraction safely skipped (cancels in
            // num/den anyway, so deferred normalization is exact)
            const float e0 = __expf(s0);
            const float zc0[4] = {bflo(z0.x), bfhi(z0.x), bflo(z0.y), bfhi(z0.y)};
            den += e0;
            #pragma unroll
            for (int c = 0; c < 4; c++) acc[c] = fmaf(e0, zc0[c], acc[c]);
            if (two) {
                const float e1 = __expf(s1);
                const float zc1[4] = {bflo(z1.x), bfhi(z1.x), bflo(z1.y), bfhi(z1.y)};
                den += e1;
                #pragma unroll
                for (int c = 0; c < 4; c++) acc[c] = fmaf(e1, zc1[c], acc[c]);
            }
        }
        const float inv = 1.f / den;
        #pragma unroll
        for (int c = 0; c < 4; c++) acc[c] *= inv;
    }

    union { uint2 u; short s[4]; } pk;
    #pragma unroll
    for (int c = 0; c < 4; c++) {
        const bf16 b = __float2bfloat16(acc[c]);
        pk.s[c] = *(const short*)&b;
    }
    *(uint2*)(agg + (size_t)v * (H_HEADS * IN_DIM) + h * IN_DIM + lane * 4) = pk.u;
}

// ---------------- fallback pair (used only if workspace too small for a
// separate agg buffer; agg then overlays fs, so score/agg must be 2 passes)
__global__ __launch_bounds__(256)
void score_csr_kernel(const f16* __restrict__ fs, const f16* __restrict__ fd,
                      const int* __restrict__ rowptr, const int* __restrict__ csr_src,
                      const f16* __restrict__ atn16, float* __restrict__ expbuf,
                      float* __restrict__ denomB, int N)
{
    const int wave = threadIdx.x >> 6;
    const int lane = threadIdx.x & 63;
    const int wgid = blockIdx.x * 4 + wave;
    const int nw   = gridDim.x * 4;

    uint4 at[H_HEADS];
    #pragma unroll
    for (int h = 0; h < H_HEADS; h++)
        at[h] = *(const uint4*)(atn16 + h * D_HEAD + lane * 8);

    for (int v = wgid; v < N; v += nw) {
        const int off0 = rowptr[v], off1 = rowptr[v + 1];
        if (off0 == off1) continue;
        uint4 fdr[H_HEADS];
        #pragma unroll
        for (int h = 0; h < H_HEADS; h++)
            fdr[h] = *(const uint4*)(fd + (size_t)v * HD + h * D_HEAD + lane * 8);

        float4 den = make_float4(0.f, 0.f, 0.f, 0.f);
        for (int o = off0; o < off1; o += 2) {
            const bool two = (o + 1 < off1);
            const int u0 = csr_src[o];
            const int u1 = two ? csr_src[o + 1] : u0;
            const f16* f0 = fs + (size_t)u0 * HD + lane * 8;
            const f16* f1 = fs + (size_t)u1 * HD + lane * 8;
            uint4 pa0[H_HEADS], pa1[H_HEADS];
            #pragma unroll
            for (int h = 0; h < H_HEADS; h++) pa0[h] = *(const uint4*)(f0 + h * D_HEAD);
            #pragma unroll
            for (int h = 0; h < H_HEADS; h++) pa1[h] = *(const uint4*)(f1 + h * D_HEAD);

            float s0[H_HEADS], s1[H_HEADS];
            #pragma unroll
            for (int h = 0; h < H_HEADS; h++) {
                s0[h] = score_head_h2(pa0[h], fdr[h], at[h]);
                s1[h] = score_head_h2(pa1[h], fdr[h], at[h]);
            }
            #pragma unroll
            for (int ofs = 32; ofs > 0; ofs >>= 1) {
                #pragma unroll
                for (int h = 0; h < H_HEADS; h++) {
                    s0[h] += __shfl_xor(s0[h], ofs, 64);
                    s1[h] += __shfl_xor(s1[h], ofs, 64);
                }
            }
            const float4 e0 = make_float4(expf(s0[0]), expf(s0[1]), expf(s0[2]), expf(s0[3]));
            den.x += e0.x; den.y += e0.y; den.z += e0.z; den.w += e0.w;
            float4 e1;
            if (two) {
                e1 = make_float4(expf(s1[0]), expf(s1[1]), expf(s1[2]), expf(s1[3]));
                den.x += e1.x; den.y += e1.y; den.z += e1.z; den.w += e1.w;
            }
            if (lane == 0) {
                *(float4*)(expbuf + (size_t)o * H_HEADS) = e0;
                if (two) *(float4*)(expbuf + (size_t)(o + 1) * H_HEADS) = e1;
            }
        }
        if (lane == 0) *(float4*)(denomB + (size_t)v * H_HEADS) = den;
    }
}

__global__ __launch_bounds__(256)
void agg_z_kernel(const bf16* __restrict__ zb, const int* __restrict__ rowptr,
                  const int* __restrict__ csr_src, const float* __restrict__ expbuf,
                  const float* __restrict__ denomB, bf16* __restrict__ agg, int N)
{
    const int wave = threadIdx.x >> 6;
    const int lane = threadIdx.x & 63;
    const int wgid = blockIdx.x * 4 + wave;
    const int nw   = gridDim.x * 4;

    for (int v = wgid; v < N; v += nw) {
        const int off0 = rowptr[v], off1 = rowptr[v + 1];
        float acc[H_HEADS][4];
        #pragma unroll
        for (int h = 0; h < H_HEADS; h++)
            #pragma unroll
            for (int c = 0; c < 4; c++) acc[h][c] = 0.f;

        if (off1 > off0) {
            const float4 den = *(const float4*)(denomB + (size_t)v * H_HEADS);
            const float4 inv = make_float4(1.f / den.x, 1.f / den.y, 1.f / den.z, 1.f / den.w);
            int o = off0;
            for (; o + 1 < off1; o += 2) {
                const float4 e0 = *(const float4*)(expbuf + (size_t)o * H_HEADS);
                const float4 e1 = *(const float4*)(expbuf + (size_t)(o + 1) * H_HEADS);
                const int u0 = csr_src[o], u1 = csr_src[o + 1];
                const uint2 z0 = *(const uint2*)(zb + (size_t)u0 * IN_DIM + lane * 4);
                const uint2 z1 = *(const uint2*)(zb + (size_t)u1 * IN_DIM + lane * 4);
                const float a0[4] = {e0.x * inv.x, e0.y * inv.y, e0.z * inv.z, e0.w * inv.w};
                const float a1[4] = {e1.x * inv.x, e1.y * inv.y, e1.z * inv.z, e1.w * inv.w};
                const float zc0[4] = {bflo(z0.x), bfhi(z0.x), bflo(z0.y), bfhi(z0.y)};
                const float zc1[4] = {bflo(z1.x), bfhi(z1.x), bflo(z1.y), bfhi(z1.y)};
                #pragma unroll
                for (int h = 0; h < H_HEADS; h++)
                    #pragma unroll
                    for (int c = 0; c < 4; c++)
                        acc[h][c] += a0[h] * zc0[c] + a1[h] * zc1[c];
            }
            if (o < off1) {
                const float4 e0 = *(const float4*)(expbuf + (size_t)o * H_HEADS);
                const int u0 = csr_src[o];
                const uint2 z0 = *(const uint2*)(zb + (size_t)u0 * IN_DIM + lane * 4);
                const float a0[4] = {e0.x * inv.x, e0.y * inv.y, e0.z * inv.z, e0.w * inv.w};
                const float zc0[4] = {bflo(z0.x), bfhi(z0.x), bflo(z0.y), bfhi(z0.y)};
                #pragma unroll
                for (int h = 0; h < H_HEADS; h++)
                    #pragma unroll
                    for (int c = 0; c < 4; c++)
                        acc[h][c] += a0[h] * zc0[c];
            }
        }
        #pragma unroll
        for (int h = 0; h < H_HEADS; h++) {
            union { uint2 u; short s[4]; } pk;
            #pragma unroll
            for (int c = 0; c < 4; c++) {
                const bf16 b = __float2bfloat16(acc[h][c]);
                pk.s[c] = *(const short*)&b;
            }
            *(uint2*)(agg + (size_t)v * (H_HEADS * IN_DIM) + h * IN_DIM + lane * 4) = pk.u;
        }
    }
}

extern "C" void kernel_launch(void* const* d_in, const int* in_sizes, int n_in,
                              void* d_out, int out_size, void* d_ws, size_t ws_size,
                              hipStream_t stream)
{
    const float* z        = (const float*)d_in[0];
    const int*   src      = (const int*)d_in[1];
    const int*   dst      = (const int*)d_in[2];
    const float* W_src    = (const float*)d_in[3];
    const float* b_src    = (const float*)d_in[4];
    const float* W_dst    = (const float*)d_in[5];
    const float* b_dst    = (const float*)d_in[6];
    const float* attn     = (const float*)d_in[7];
    const float* gat_bias = (const float*)d_in[8];
    const float* W_fc     = (const float*)d_in[9];
    const float* b_fc     = (const float*)d_in[10];
    float* out = (float*)d_out;

    const int N = in_sizes[0] / IN_DIM;   // 20000
    const int E = in_sizes[1];            // 100000

    // Workspace (~184 MB base; +41 MB for separate agg if ws_size allows).
    char* p = (char*)d_ws;
    const size_t featB = (size_t)N * HD * 2;
    f16* fs       = (f16*)p;   p += featB;                               // 81.92 MB (f16)
    f16* fd       = (f16*)p;   p += featB;                               // 81.92 MB (f16)
    bf16* zb      = (bf16*)p;  p += (size_t)N * IN_DIM * sizeof(bf16);   // 10.24 MB
    bf16* WsbT    = (bf16*)p;  p += (size_t)HD * IN_DIM * sizeof(bf16);  // 1.05 MB
    bf16* WdbT    = (bf16*)p;  p += (size_t)HD * IN_DIM * sizeof(bf16);  // 1.05 MB
    bf16* Wsb     = (bf16*)p;  p += (size_t)IN_DIM * HD * sizeof(bf16);  // 1.05 MB
    bf16* WfcT    = (bf16*)p;  p += (size_t)HD * D_HEAD * sizeof(bf16);  // 2.10 MB
    bf16* Wfinal  = (bf16*)p;  p += (size_t)OUTD * 1024 * sizeof(bf16);  // 1.05 MB
    float* bias_cat = (float*)p; p += (size_t)2 * HD * sizeof(float);    // 16 KB
    f16* atn16    = (f16*)p;   p += (size_t)HD * sizeof(f16);            // 4 KB
    float* bsW_tot = (float*)p; p += (size_t)OUTD * sizeof(float);
    float* cvec   = (float*)p; p += (size_t)OUTD * sizeof(float);
    float* expbuf = (float*)p; p += (size_t)E * H_HEADS * sizeof(float); // 1.6 MB
    float* denomB = (float*)p; p += (size_t)N * H_HEADS * sizeof(float); // 0.32 MB
    int* cnt      = (int*)p;   p += ((size_t)N * 4 + 15) & ~15ULL;
    int* rowptr   = (int*)p;   p += ((size_t)(N + 1) * 4 + 15) & ~15ULL;
    int* cursor   = (int*)p;   p += ((size_t)N * 4 + 15) & ~15ULL;
    int* csr_src  = (int*)p;   p += ((size_t)E * 4 + 15) & ~15ULL;

    // Separate agg buffer (fused score+agg needs fs live while writing agg);
    // fall back to overlaying fs + 2-pass kernels if workspace is too small.
    bf16* aggSep = (bf16*)p;
    const size_t needFused = (size_t)(p - (char*)d_ws) + (size_t)N * (H_HEADS * IN_DIM) * sizeof(bf16);
    const bool fused = (ws_size >= needFused);
    bf16* agg = fused ? aggSep : (bf16*)fs;

    // Prep: weight casts/transposes + bias concat + attn f16 + cnt zero,
    // plus cvec/bsW_tot reductions in an extra block range.
    const int prepElems  = 524288 * 3 + 1048576 + 2 * HD + HD + N;
    const int prepBlocks = (prepElems + 255) / 256;
    prep_kernel<<<prepBlocks + 2 * OUTD, 256, 0, stream>>>(
        W_src, W_dst, W_fc, b_src, b_dst, attn, b_fc, gat_bias,
        WsbT, WdbT, WfcT, Wsb, bias_cat, atn16, cnt, N, cvec, bsW_tot, prepBlocks);

    // z cast + degree histogram (one launch)
    const long n4 = (long)N * IN_DIM / 4;
    cast_hist_kernel<<<(int)((n4 + E + 255) / 256), 256, 0, stream>>>(z, zb, n4, dst, cnt, E);

    // CSR build (scan also emits cursor)
    scan_kernel<<<1, 1024, 0, stream>>>(cnt, rowptr, cursor, N);
    scatter_kernel<<<(E + 255) / 256, 256, 0, stream>>>(src, dst, cursor, csr_src, E);

    // Wfinal[j, h*256+k] = Wcomb_h[k, j]
    mfma_gemm_kernel<0><<<dim3(IN_DIM / 128, D_HEAD / 128, H_HEADS), 256, 0, stream>>>(
        WfcT, D_HEAD, (long)D_HEAD * D_HEAD,
        Wsb, HD, (long)D_HEAD,
        nullptr, 0, nullptr, nullptr,
        Wfinal, 1024, (long)IN_DIM,
        D_HEAD, D_HEAD);

    // fs,fd = zb @ {W_src,W_dst} + {b_src,b_dst}, f16 output (one z=2 dispatch)
    mfma_gemm_kernel<2><<<dim3(HD / 128, (N + 127) / 128, 2), 256, 0, stream>>>(
        zb, IN_DIM, 0L,
        WsbT, IN_DIM, (long)HD * IN_DIM,
        bias_cat, (long)HD, nullptr, nullptr,
        fs, HD, (long)N * HD,
        N, IN_DIM);

    // Edge scores + z-space aggregation
    if (fused) {
        score_agg_kernel<<<N, 256, 0, stream>>>(fs, fd, zb, rowptr, csr_src, atn16, agg, N);
    } else {
        score_csr_kernel<<<2500, 256, 0, stream>>>(fs, fd, rowptr, csr_src, atn16, expbuf, denomB, N);
        agg_z_kernel<<<2500, 256, 0, stream>>>(zb, rowptr, csr_src, expbuf, denomB, agg, N);
    }

    // out = lrelu(agg @ Wfinal^T + cvec + deg?bsW_tot), fused epilogue
    mfma_gemm_kernel<1><<<dim3(OUTD / 128, (N + 127) / 128, 1), 256, 0, stream>>>(
        agg, H_HEADS * IN_DIM, 0L,
        Wfinal, H_HEADS * IN_DIM, 0L,
        cvec, 0L, bsW_tot, rowptr,
        out, OUTD, 0L,
        N, H_HEADS * IN_DIM);
}

// Round 3
// 365.687 us; speedup vs baseline: 1.1152x; 1.0321x over previous
//
#include <hip/hip_runtime.h>
#include <hip/hip_bf16.h>
#include <math.h>

#define H_HEADS 4
#define D_HEAD 512
#define HD 2048
#define IN_DIM 256
#define OUTD 512
#define NEG 0.2f

typedef __hip_bfloat16 bf16;
typedef _Float16 f16;
typedef __attribute__((ext_vector_type(2))) _Float16 h2v;  // packed fp16 pair
typedef __attribute__((ext_vector_type(8))) short s16x8;   // 8 x bf16 (4 VGPRs)
typedef __attribute__((ext_vector_type(4))) float f32x4;   // MFMA accumulator

__device__ __forceinline__ float bflo(unsigned w) { union { unsigned u; float f; } x; x.u = w << 16; return x.f; }
__device__ __forceinline__ float bfhi(unsigned w) { union { unsigned u; float f; } x; x.u = w & 0xffff0000u; return x.f; }

// ---------------- batched MFMA bf16 GEMM ----------------
// C_z[row, col] = sum_k A_z[row, k] * Bt_z[col, k]
// MODE 0: bf16 output, + bias[col].
// MODE 1: fp32 output, fused: lrelu(acc + bias[col] + (deg(row)>0 ? bias2[col] : 0)).
// MODE 2: f16 output, + bias[col].
// Tile 128x128, BK=32; staging rows clamped to M-1 (never stored OOB).
// LDS bank-conflict fix: chunk index XOR-swizzled by (row>>1)&3 on both the
// staging global-source side and the fragment-read side.
// K-loop is 2-PHASE DOUBLE-BUFFERED (catalog T3-minimum): STAGE of tile t+1 is
// issued BEFORE the ds_read+MFMA of tile t, so the vmcnt(0) drain at the
// end-of-iter barrier lands after the compute phase instead of before it.
// Staging = 2 x (A 8KB + B 8KB) = 32KB, under the 34.8KB epilogue buffer ->
// LDS block size and occupancy unchanged.
// 16-bit epilogue is SINGLE-PHASE: all 4 waves write their 64x64 quadrant into
// a full 128x136 LDS buffer, one barrier, then 8 coalesced store iterations.
template<int MODE>
__global__ __launch_bounds__(256)
void mfma_gemm_kernel(const bf16* __restrict__ A, int lda, long aOff,
                      const bf16* __restrict__ Bt, int ldb, long bOff,
                      const float* __restrict__ bias, long biasOff,
                      const float* __restrict__ bias2, const int* __restrict__ rowptr,
                      void* __restrict__ Cv, int ldc, long cOff,
                      int M, int K)
{
    constexpr int SMEM_BYTES = (MODE == 1) ? (64 * 132 * 4) : (128 * 136 * 2);
    static_assert(SMEM_BYTES >= 4 * 4096 * 2, "staging dbuf must fit");
    __shared__ __align__(16) char smem_raw[SMEM_BYTES];
    bf16* stg = (bf16*)smem_raw;   // [2][A:4096 | B:4096] elements

    const int tid  = threadIdx.x;
    const int r0   = blockIdx.y * 128;
    const int n0   = blockIdx.x * 128;
    const int z    = blockIdx.z;
    const int lane = tid & 63;
    const int wave = tid >> 6;
    const int wr   = (wave >> 1) * 64;
    const int wc   = (wave & 1) * 64;
    const int l15  = lane & 15;
    const int quad = lane >> 4;

    const bf16* Az = A + aOff * (long)z;
    const bf16* Bz = Bt + bOff * (long)z;

    f32x4 acc[4][4];
    #pragma unroll
    for (int i = 0; i < 4; i++)
        #pragma unroll
        for (int j = 0; j < 4; j++)
            #pragma unroll
            for (int r = 0; r < 4; r++) acc[i][j][r] = 0.f;

    const int srow = tid >> 2;
    // XOR-swizzle: this lane fetches global chunk (k8 ^ key(row)); same 64B window.
    const int skof = (((tid & 3) ^ ((srow >> 1) & 3)) * 8);
    const int swz  = (l15 >> 1) & 3;   // reader-side key: row&15 == l15

    auto stage_tile = [&](int c, int k0) {
        bf16* As = stg + c * 8192;
        bf16* Bs = As + 4096;
        #pragma unroll
        for (int p = 0; p < 2; p++) {
            int ar = r0 + p * 64 + srow;
            if (ar >= M) ar = M - 1;
            const bf16* ga = Az + (size_t)ar * lda + k0 + skof;
            __builtin_amdgcn_global_load_lds(
                (const __attribute__((address_space(1))) void*)ga,
                (__attribute__((address_space(3))) void*)(As + (p * 256 + tid) * 8),
                16, 0, 0);
            const bf16* gb = Bz + (size_t)(n0 + p * 64 + srow) * ldb + k0 + skof;
            __builtin_amdgcn_global_load_lds(
                (const __attribute__((address_space(1))) void*)gb,
                (__attribute__((address_space(3))) void*)(Bs + (p * 256 + tid) * 8),
                16, 0, 0);
        }
    };

    stage_tile(0, 0);
    __syncthreads();               // buf0 resident
    int cbuf = 0;
    for (int k0 = 0; k0 < K; k0 += 32) {
        if (k0 + 32 < K) stage_tile(cbuf ^ 1, k0 + 32);   // prefetch next tile

        const bf16* As = stg + cbuf * 8192;
        const bf16* Bs = As + 4096;
        s16x8 af[4], bg[4];
        #pragma unroll
        for (int i = 0; i < 4; i++)
            af[i] = *(const s16x8*)(As + (wr + i * 16 + l15) * 32 + (quad ^ swz) * 8);
        #pragma unroll
        for (int j = 0; j < 4; j++)
            bg[j] = *(const s16x8*)(Bs + (wc + j * 16 + l15) * 32 + (quad ^ swz) * 8);
        #pragma unroll
        for (int i = 0; i < 4; i++)
            #pragma unroll
            for (int j = 0; j < 4; j++)
                acc[i][j] = __builtin_amdgcn_mfma_f32_16x16x32_bf16(af[i], bg[j], acc[i][j], 0, 0, 0);
        __syncthreads();           // drains prefetch (post-compute) + guards buf reuse
        cbuf ^= 1;
    }

    // C/D frag layout: col = lane&15, row = quad*4 + reg (m89/m91 verified)
    if (MODE == 0 || MODE == 2) {
        float bv[4];
        #pragma unroll
        for (int j = 0; j < 4; j++)
            bv[j] = bias ? bias[biasOff * (long)z + n0 + wc + j * 16 + l15] : 0.f;

        const long cb = cOff * (long)z;

        // single-phase transpose: every wave writes its own quadrant
        if (MODE == 0) {
            bf16* Cs = (bf16*)smem_raw;
            #pragma unroll
            for (int i = 0; i < 4; i++)
                #pragma unroll
                for (int j = 0; j < 4; j++)
                    #pragma unroll
                    for (int r = 0; r < 4; r++)
                        Cs[(wr + i * 16 + quad * 4 + r) * 136 + wc + j * 16 + l15] =
                            __float2bfloat16(acc[i][j][r] + bv[j]);
        } else {
            f16* Cs = (f16*)smem_raw;
            #pragma unroll
            for (int i = 0; i < 4; i++)
                #pragma unroll
                for (int j = 0; j < 4; j++)
                    #pragma unroll
                    for (int r = 0; r < 4; r++)
                        Cs[(wr + i * 16 + quad * 4 + r) * 136 + wc + j * 16 + l15] =
                            (f16)(acc[i][j][r] + bv[j]);
        }
        __syncthreads();
        #pragma unroll
        for (int it = 0; it < 8; it++) {
            const int idx  = it * 256 + tid;
            const int lrow = idx >> 4;
            const int lcol = (idx & 15) * 8;
            const int grow = r0 + lrow;
            if (grow < M)
                *(uint4*)((short*)Cv + cb + (size_t)grow * ldc + n0 + lcol) =
                    *(const uint4*)((const short*)smem_raw + lrow * 136 + lcol);
        }
    } else {
        float* C = (float*)Cv;
        float* Csf = (float*)smem_raw;     // 64 x 132 (padded)

        #pragma unroll
        for (int p = 0; p < 2; p++) {
            __syncthreads();
            if (wr == p * 64) {
                #pragma unroll
                for (int i = 0; i < 4; i++)
                    #pragma unroll
                    for (int j = 0; j < 4; j++)
                        #pragma unroll
                        for (int r = 0; r < 4; r++)
                            Csf[(i * 16 + quad * 4 + r) * 132 + wc + j * 16 + l15] = acc[i][j][r];
            }
            __syncthreads();
            #pragma unroll
            for (int it = 0; it < 8; it++) {
                const int idx  = it * 256 + tid;
                const int lrow = idx >> 5;
                const int lcol = (idx & 31) * 4;
                const int grow = r0 + p * 64 + lrow;
                if (grow < M) {
                    const int gcol = n0 + lcol;
                    float4 v  = *(const float4*)(Csf + lrow * 132 + lcol);
                    const float4 c4 = *(const float4*)(bias + gcol);
                    const float4 b4 = *(const float4*)(bias2 + gcol);
                    const bool has = rowptr[grow + 1] > rowptr[grow];
                    v.x += c4.x + (has ? b4.x : 0.f);
                    v.y += c4.y + (has ? b4.y : 0.f);
                    v.z += c4.z + (has ? b4.z : 0.f);
                    v.w += c4.w + (has ? b4.w : 0.f);
                    v.x = v.x > 0.f ? v.x : NEG * v.x;
                    v.y = v.y > 0.f ? v.y : NEG * v.y;
                    v.z = v.z > 0.f ? v.z : NEG * v.z;
                    v.w = v.w > 0.f ? v.w : NEG * v.w;
                    *(float4*)(C + (size_t)grow * ldc + gcol) = v;
                }
            }
        }
    }
}

// ---------------- prep: casts / transposes / bias concat / attn-f16 / cnt-zero
// plus (extra block range) the two 2048-dot reductions (cvec / bsW_tot).
__global__ __launch_bounds__(256)
void prep_kernel(const float* __restrict__ W_src, const float* __restrict__ W_dst,
                 const float* __restrict__ W_fc, const float* __restrict__ b_src,
                 const float* __restrict__ b_dst, const float* __restrict__ attn,
                 const float* __restrict__ b_fc, const float* __restrict__ gat_bias,
                 bf16* __restrict__ WsbT, bf16* __restrict__ WdbT,
                 bf16* __restrict__ WfcT, bf16* __restrict__ Wsb,
                 float* __restrict__ bias_cat, f16* __restrict__ atn16,
                 int* __restrict__ cnt, int nCnt,
                 float* __restrict__ cvec, float* __restrict__ bsW_tot, int prepBlocks)
{
    __shared__ float red[256];
    if ((int)blockIdx.x >= prepBlocks) {
        // reduction role: cvec[j] = gat_bias @ W_fc[:,j] + b_fc[j]  (b < OUTD)
        //                 bsW_tot[j] = b_src @ W_fc[:,j]            (b >= OUTD)
        const int b = blockIdx.x - prepBlocks;
        const int t = threadIdx.x;
        const bool isCvec = b < OUTD;
        const int j = isCvec ? b : b - OUTD;
        const float* vec = isCvec ? gat_bias : b_src;
        float s = 0.f;
        for (int k = t; k < HD; k += 256)
            s = fmaf(vec[k], W_fc[(size_t)k * OUTD + j], s);
        red[t] = s;
        __syncthreads();
        for (int o = 128; o > 0; o >>= 1) {
            if (t < o) red[t] += red[t + o];
            __syncthreads();
        }
        if (t == 0) {
            if (isCvec) cvec[j] = red[0] + b_fc[j];
            else bsW_tot[j] = red[0];
        }
        return;
    }
    int idx = blockIdx.x * 256 + threadIdx.x;
    if (idx < 524288) {
        const int n = idx >> 8, k = idx & 255;
        WsbT[idx] = __float2bfloat16(W_src[(size_t)k * HD + n]);
        return;
    }
    idx -= 524288;
    if (idx < 524288) {
        const int n = idx >> 8, k = idx & 255;
        WdbT[idx] = __float2bfloat16(W_dst[(size_t)k * HD + n]);
        return;
    }
    idx -= 524288;
    if (idx < 1048576) {
        const int n = idx >> 9, t = idx & 511;      // n = h*512 + j
        const int h = n >> 9, j = n & 511;
        WfcT[idx] = __float2bfloat16(W_fc[(size_t)(h * 512 + t) * OUTD + j]);
        return;
    }
    idx -= 1048576;
    if (idx < 524288) {
        Wsb[idx] = __float2bfloat16(W_src[idx]);
        return;
    }
    idx -= 524288;
    if (idx < 2 * HD) {
        bias_cat[idx] = (idx < HD) ? b_src[idx] : b_dst[idx - HD];
        return;
    }
    idx -= 2 * HD;
    if (idx < HD) {
        atn16[idx] = (f16)attn[idx];
        return;
    }
    idx -= HD;
    if (idx < nCnt) cnt[idx] = 0;
}

// cast z -> bf16, plus (tail range) degree histogram (cnt zeroed by prep)
__global__ void cast_hist_kernel(const float* __restrict__ S, bf16* __restrict__ T,
                                 long n4, const int* __restrict__ dst,
                                 int* __restrict__ cnt, int E)
{
    long t = (long)blockIdx.x * 256 + threadIdx.x;
    if (t < n4) {
        const long i = t * 4;
        const float4 v = *(const float4*)(S + i);
        T[i + 0] = __float2bfloat16(v.x);
        T[i + 1] = __float2bfloat16(v.y);
        T[i + 2] = __float2bfloat16(v.z);
        T[i + 3] = __float2bfloat16(v.w);
        return;
    }
    t -= n4;
    if (t < E) atomicAdd(&cnt[dst[t]], 1);
}

// single-workgroup scan, shfl-based wave scans; emits cursor[] (= rowptr) too.
__global__ __launch_bounds__(1024)
void scan_kernel(const int* __restrict__ cnt, int* __restrict__ rowptr,
                 int* __restrict__ cursor, int n)
{
    __shared__ int wsum[16];
    __shared__ int carry_s;
    const int tid  = threadIdx.x;
    const int lane = tid & 63;
    const int wv   = tid >> 6;
    if (tid == 0) { carry_s = 0; rowptr[0] = 0; cursor[0] = 0; }
    __syncthreads();
    for (int base = 0; base < n; base += 1024) {
        const int i = base + tid;
        int v = (i < n) ? cnt[i] : 0;
        #pragma unroll
        for (int d = 1; d < 64; d <<= 1) {
            const int t = __shfl_up(v, d, 64);
            if (lane >= d) v += t;
        }
        if (lane == 63) wsum[wv] = v;
        __syncthreads();
        if (tid < 16) {
            int w = wsum[tid];
            #pragma unroll
            for (int d = 1; d < 16; d <<= 1) {
                const int t = __shfl_up(w, d, 64);
                if (tid >= d) w += t;
            }
            wsum[tid] = w;
        }
        __syncthreads();
        const int incl = v + (wv ? wsum[wv - 1] : 0) + carry_s;
        if (i < n) {
            rowptr[i + 1] = incl;
            if (i + 1 < n) cursor[i + 1] = incl;
        }
        __syncthreads();                 // all reads of carry_s / wsum done
        if (tid == 1023) carry_s += wsum[15];
        __syncthreads();                 // carry_s/wsum safe for next chunk
    }
}

__global__ void scatter_kernel(const int* __restrict__ src, const int* __restrict__ dst,
                               int* __restrict__ cursor, int* __restrict__ csr_src, int E)
{
    const int e = blockIdx.x * 256 + threadIdx.x;
    if (e >= E) return;
    const int pos = atomicAdd(&cursor[dst[e]], 1);
    csr_src[pos] = src[e];
}

// ---------------- edge scores: packed-f16 math ----------------
// LeakyReLU(s, 0.2) == 0.6*s + 0.4*|s|, branch-free; |s| via sign-bit mask on
// the packed word. All ops compile to v_pk_{add,mul,fma}_f16.
__device__ __forceinline__ float score_head_h2(const uint4 pa, const uint4 pb, const uint4 at)
{
    const unsigned* ua = (const unsigned*)&pa;
    const unsigned* ub = (const unsigned*)&pb;
    const unsigned* ut = (const unsigned*)&at;
    h2v acc = (h2v)(_Float16)0.f;
    const h2v c06 = (h2v)(_Float16)0.6f;
    const h2v c04 = (h2v)(_Float16)0.4f;
    #pragma unroll
    for (int c = 0; c < 4; c++) {
        union { unsigned u; h2v h; } A, B, T, S, Ab;
        A.u = ua[c]; B.u = ub[c]; T.u = ut[c];
        S.h = A.h + B.h;
        Ab.u = S.u & 0x7fff7fffu;
        const h2v l = S.h * c06 + Ab.h * c04;
        acc += l * T.h;
    }
    return (float)acc.x + (float)acc.y;
}

// ---------------- FUSED score + z-space aggregation, per-(node,head) ----------------
// block = node, wave = head. The 4 head-waves walk the same edge list ->
// csr_src/zb re-reads are L1 broadcasts, no extra HBM traffic.
// agg[v, h*256+k] = (sum_e exp(s_eh) * zb[u_e, k]) / (sum_e exp(s_eh))
__global__ __launch_bounds__(256)
void score_agg_kernel(const f16* __restrict__ fs, const f16* __restrict__ fd,
                      const bf16* __restrict__ zb,
                      const int* __restrict__ rowptr, const int* __restrict__ csr_src,
                      const f16* __restrict__ atn16, bf16* __restrict__ agg, int N)
{
    const int h    = threadIdx.x >> 6;     // wave index = head
    const int lane = threadIdx.x & 63;
    const int v    = blockIdx.x;
    if (v >= N) return;

    const uint4 at = *(const uint4*)(atn16 + h * D_HEAD + lane * 8);
    const f16* fsh = fs + h * D_HEAD + lane * 8;

    const int off0 = rowptr[v], off1 = rowptr[v + 1];
    float acc[4] = {0.f, 0.f, 0.f, 0.f};

    if (off1 > off0) {
        const uint4 fdr = *(const uint4*)(fd + (size_t)v * HD + h * D_HEAD + lane * 8);
        float den = 0.f;
        for (int o = off0; o < off1; o += 2) {
            const bool two = (o + 1 < off1);
            const int u0 = csr_src[o];
            const int u1 = two ? csr_src[o + 1] : u0;
            const uint4 pa0 = *(const uint4*)(fsh + (size_t)u0 * HD);
            const uint4 pa1 = *(const uint4*)(fsh + (size_t)u1 * HD);
            const uint2 z0 = *(const uint2*)(zb + (size_t)u0 * IN_DIM + lane * 4);
            const uint2 z1 = *(const uint2*)(zb + (size_t)u1 * IN_DIM + lane * 4);

            float s0 = score_head_h2(pa0, fdr, at);
            float s1 = score_head_h2(pa1, fdr, at);
            #pragma unroll
            for (int ofs = 32; ofs > 0; ofs >>= 1) {
                s0 += __shfl_xor(s0, ofs, 64);
                s1 += __shfl_xor(s1, ofs, 64);
            }
            // scores O(0.2): max-subtraction safely skipped (cancels in
            // num/den anyway, so deferred normalization is exact)
            const float e0 = __expf(s0);
            const float zc0[4] = {bflo(z0.x), bfhi(z0.x), bflo(z0.y), bfhi(z0.y)};
            den += e0;
            #pragma unroll
            for (int c = 0; c < 4; c++) acc[c] = fmaf(e0, zc0[c], acc[c]);
            if (two) {
                const float e1 = __expf(s1);
                const float zc1[4] = {bflo(z1.x), bfhi(z1.x), bflo(z1.y), bfhi(z1.y)};
                den += e1;
                #pragma unroll
                for (int c = 0; c < 4; c++) acc[c] = fmaf(e1, zc1[c], acc[c]);
            }
        }
        const float inv = 1.f / den;
        #pragma unroll
        for (int c = 0; c < 4; c++) acc[c] *= inv;
    }

    union { uint2 u; short s[4]; } pk;
    #pragma unroll
    for (int c = 0; c < 4; c++) {
        const bf16 b = __float2bfloat16(acc[c]);
        pk.s[c] = *(const short*)&b;
    }
    *(uint2*)(agg + (size_t)v * (H_HEADS * IN_DIM) + h * IN_DIM + lane * 4) = pk.u;
}

// ---------------- fallback pair (used only if workspace too small for a
// separate agg buffer; agg then overlays fs, so score/agg must be 2 passes)
__global__ __launch_bounds__(256)
void score_csr_kernel(const f16* __restrict__ fs, const f16* __restrict__ fd,
                      const int* __restrict__ rowptr, const int* __restrict__ csr_src,
                      const f16* __restrict__ atn16, float* __restrict__ expbuf,
                      float* __restrict__ denomB, int N)
{
    const int wave = threadIdx.x >> 6;
    const int lane = threadIdx.x & 63;
    const int wgid = blockIdx.x * 4 + wave;
    const int nw   = gridDim.x * 4;

    uint4 at[H_HEADS];
    #pragma unroll
    for (int h = 0; h < H_HEADS; h++)
        at[h] = *(const uint4*)(atn16 + h * D_HEAD + lane * 8);

    for (int v = wgid; v < N; v += nw) {
        const int off0 = rowptr[v], off1 = rowptr[v + 1];
        if (off0 == off1) continue;
        uint4 fdr[H_HEADS];
        #pragma unroll
        for (int h = 0; h < H_HEADS; h++)
            fdr[h] = *(const uint4*)(fd + (size_t)v * HD + h * D_HEAD + lane * 8);

        float4 den = make_float4(0.f, 0.f, 0.f, 0.f);
        for (int o = off0; o < off1; o += 2) {
            const bool two = (o + 1 < off1);
            const int u0 = csr_src[o];
            const int u1 = two ? csr_src[o + 1] : u0;
            const f16* f0 = fs + (size_t)u0 * HD + lane * 8;
            const f16* f1 = fs + (size_t)u1 * HD + lane * 8;
            uint4 pa0[H_HEADS], pa1[H_HEADS];
            #pragma unroll
            for (int h = 0; h < H_HEADS; h++) pa0[h] = *(const uint4*)(f0 + h * D_HEAD);
            #pragma unroll
            for (int h = 0; h < H_HEADS; h++) pa1[h] = *(const uint4*)(f1 + h * D_HEAD);

            float s0[H_HEADS], s1[H_HEADS];
            #pragma unroll
            for (int h = 0; h < H_HEADS; h++) {
                s0[h] = score_head_h2(pa0[h], fdr[h], at[h]);
                s1[h] = score_head_h2(pa1[h], fdr[h], at[h]);
            }
            #pragma unroll
            for (int ofs = 32; ofs > 0; ofs >>= 1) {
                #pragma unroll
                for (int h = 0; h < H_HEADS; h++) {
                    s0[h] += __shfl_xor(s0[h], ofs, 64);
                    s1[h] += __shfl_xor(s1[h], ofs, 64);
                }
            }
            const float4 e0 = make_float4(expf(s0[0]), expf(s0[1]), expf(s0[2]), expf(s0[3]));
            den.x += e0.x; den.y += e0.y; den.z += e0.z; den.w += e0.w;
            float4 e1;
            if (two) {
                e1 = make_float4(expf(s1[0]), expf(s1[1]), expf(s1[2]), expf(s1[3]));
                den.x += e1.x; den.y += e1.y; den.z += e1.z; den.w += e1.w;
            }
            if (lane == 0) {
                *(float4*)(expbuf + (size_t)o * H_HEADS) = e0;
                if (two) *(float4*)(expbuf + (size_t)(o + 1) * H_HEADS) = e1;
            }
        }
        if (lane == 0) *(float4*)(denomB + (size_t)v * H_HEADS) = den;
    }
}

__global__ __launch_bounds__(256)
void agg_z_kernel(const bf16* __restrict__ zb, const int* __restrict__ rowptr,
                  const int* __restrict__ csr_src, const float* __restrict__ expbuf,
                  const float* __restrict__ denomB, bf16* __restrict__ agg, int N)
{
    const int wave = threadIdx.x >> 6;
    const int lane = threadIdx.x & 63;
    const int wgid = blockIdx.x * 4 + wave;
    const int nw   = gridDim.x * 4;

    for (int v = wgid; v < N; v += nw) {
        const int off0 = rowptr[v], off1 = rowptr[v + 1];
        float acc[H_HEADS][4];
        #pragma unroll
        for (int h = 0; h < H_HEADS; h++)
            #pragma unroll
            for (int c = 0; c < 4; c++) acc[h][c] = 0.f;

        if (off1 > off0) {
            const float4 den = *(const float4*)(denomB + (size_t)v * H_HEADS);
            const float4 inv = make_float4(1.f / den.x, 1.f / den.y, 1.f / den.z, 1.f / den.w);
            int o = off0;
            for (; o + 1 < off1; o += 2) {
                const float4 e0 = *(const float4*)(expbuf + (size_t)o * H_HEADS);
                const float4 e1 = *(const float4*)(expbuf + (size_t)(o + 1) * H_HEADS);
                const int u0 = csr_src[o], u1 = csr_src[o + 1];
                const uint2 z0 = *(const uint2*)(zb + (size_t)u0 * IN_DIM + lane * 4);
                const uint2 z1 = *(const uint2*)(zb + (size_t)u1 * IN_DIM + lane * 4);
                const float a0[4] = {e0.x * inv.x, e0.y * inv.y, e0.z * inv.z, e0.w * inv.w};
                const float a1[4] = {e1.x * inv.x, e1.y * inv.y, e1.z * inv.z, e1.w * inv.w};
                const float zc0[4] = {bflo(z0.x), bfhi(z0.x), bflo(z0.y), bfhi(z0.y)};
                const float zc1[4] = {bflo(z1.x), bfhi(z1.x), bflo(z1.y), bfhi(z1.y)};
                #pragma unroll
                for (int h = 0; h < H_HEADS; h++)
                    #pragma unroll
                    for (int c = 0; c < 4; c++)
                        acc[h][c] += a0[h] * zc0[c] + a1[h] * zc1[c];
            }
            if (o < off1) {
                const float4 e0 = *(const float4*)(expbuf + (size_t)o * H_HEADS);
                const int u0 = csr_src[o];
                const uint2 z0 = *(const uint2*)(zb + (size_t)u0 * IN_DIM + lane * 4);
                const float a0[4] = {e0.x * inv.x, e0.y * inv.y, e0.z * inv.z, e0.w * inv.w};
                const float zc0[4] = {bflo(z0.x), bfhi(z0.x), bflo(z0.y), bfhi(z0.y)};
                #pragma unroll
                for (int h = 0; h < H_HEADS; h++)
                    #pragma unroll
                    for (int c = 0; c < 4; c++)
                        acc[h][c] += a0[h] * zc0[c];
            }
        }
        #pragma unroll
        for (int h = 0; h < H_HEADS; h++) {
            union { uint2 u; short s[4]; } pk;
            #pragma unroll
            for (int c = 0; c < 4; c++) {
                const bf16 b = __float2bfloat16(acc[h][c]);
                pk.s[c] = *(const short*)&b;
            }
            *(uint2*)(agg + (size_t)v * (H_HEADS * IN_DIM) + h * IN_DIM + lane * 4) = pk.u;
        }
    }
}

extern "C" void kernel_launch(void* const* d_in, const int* in_sizes, int n_in,
                              void* d_out, int out_size, void* d_ws, size_t ws_size,
                              hipStream_t stream)
{
    const float* z        = (const float*)d_in[0];
    const int*   src      = (const int*)d_in[1];
    const int*   dst      = (const int*)d_in[2];
    const float* W_src    = (const float*)d_in[3];
    const float* b_src    = (const float*)d_in[4];
    const float* W_dst    = (const float*)d_in[5];
    const float* b_dst    = (const float*)d_in[6];
    const float* attn     = (const float*)d_in[7];
    const float* gat_bias = (const float*)d_in[8];
    const float* W_fc     = (const float*)d_in[9];
    const float* b_fc     = (const float*)d_in[10];
    float* out = (float*)d_out;

    const int N = in_sizes[0] / IN_DIM;   // 20000
    const int E = in_sizes[1];            // 100000

    // Workspace (~184 MB base; +41 MB for separate agg if ws_size allows).
    char* p = (char*)d_ws;
    const size_t featB = (size_t)N * HD * 2;
    f16* fs       = (f16*)p;   p += featB;                               // 81.92 MB (f16)
    f16* fd       = (f16*)p;   p += featB;                               // 81.92 MB (f16)
    bf16* zb      = (bf16*)p;  p += (size_t)N * IN_DIM * sizeof(bf16);   // 10.24 MB
    bf16* WsbT    = (bf16*)p;  p += (size_t)HD * IN_DIM * sizeof(bf16);  // 1.05 MB
    bf16* WdbT    = (bf16*)p;  p += (size_t)HD * IN_DIM * sizeof(bf16);  // 1.05 MB
    bf16* Wsb     = (bf16*)p;  p += (size_t)IN_DIM * HD * sizeof(bf16);  // 1.05 MB
    bf16* WfcT    = (bf16*)p;  p += (size_t)HD * D_HEAD * sizeof(bf16);  // 2.10 MB
    bf16* Wfinal  = (bf16*)p;  p += (size_t)OUTD * 1024 * sizeof(bf16);  // 1.05 MB
    float* bias_cat = (float*)p; p += (size_t)2 * HD * sizeof(float);    // 16 KB
    f16* atn16    = (f16*)p;   p += (size_t)HD * sizeof(f16);            // 4 KB
    float* bsW_tot = (float*)p; p += (size_t)OUTD * sizeof(float);
    float* cvec   = (float*)p; p += (size_t)OUTD * sizeof(float);
    float* expbuf = (float*)p; p += (size_t)E * H_HEADS * sizeof(float); // 1.6 MB
    float* denomB = (float*)p; p += (size_t)N * H_HEADS * sizeof(float); // 0.32 MB
    int* cnt      = (int*)p;   p += ((size_t)N * 4 + 15) & ~15ULL;
    int* rowptr   = (int*)p;   p += ((size_t)(N + 1) * 4 + 15) & ~15ULL;
    int* cursor   = (int*)p;   p += ((size_t)N * 4 + 15) & ~15ULL;
    int* csr_src  = (int*)p;   p += ((size_t)E * 4 + 15) & ~15ULL;

    // Separate agg buffer (fused score+agg needs fs live while writing agg);
    // fall back to overlaying fs + 2-pass kernels if workspace is too small.
    bf16* aggSep = (bf16*)p;
    const size_t needFused = (size_t)(p - (char*)d_ws) + (size_t)N * (H_HEADS * IN_DIM) * sizeof(bf16);
    const bool fused = (ws_size >= needFused);
    bf16* agg = fused ? aggSep : (bf16*)fs;

    // Prep: weight casts/transposes + bias concat + attn f16 + cnt zero,
    // plus cvec/bsW_tot reductions in an extra block range.
    const int prepElems  = 524288 * 3 + 1048576 + 2 * HD + HD + N;
    const int prepBlocks = (prepElems + 255) / 256;
    prep_kernel<<<prepBlocks + 2 * OUTD, 256, 0, stream>>>(
        W_src, W_dst, W_fc, b_src, b_dst, attn, b_fc, gat_bias,
        WsbT, WdbT, WfcT, Wsb, bias_cat, atn16, cnt, N, cvec, bsW_tot, prepBlocks);

    // z cast + degree histogram (one launch)
    const long n4 = (long)N * IN_DIM / 4;
    cast_hist_kernel<<<(int)((n4 + E + 255) / 256), 256, 0, stream>>>(z, zb, n4, dst, cnt, E);

    // CSR build (scan also emits cursor)
    scan_kernel<<<1, 1024, 0, stream>>>(cnt, rowptr, cursor, N);
    scatter_kernel<<<(E + 255) / 256, 256, 0, stream>>>(src, dst, cursor, csr_src, E);

    // Wfinal[j, h*256+k] = Wcomb_h[k, j]
    mfma_gemm_kernel<0><<<dim3(IN_DIM / 128, D_HEAD / 128, H_HEADS), 256, 0, stream>>>(
        WfcT, D_HEAD, (long)D_HEAD * D_HEAD,
        Wsb, HD, (long)D_HEAD,
        nullptr, 0, nullptr, nullptr,
        Wfinal, 1024, (long)IN_DIM,
        D_HEAD, D_HEAD);

    // fs,fd = zb @ {W_src,W_dst} + {b_src,b_dst}, f16 output (one z=2 dispatch)
    mfma_gemm_kernel<2><<<dim3(HD / 128, (N + 127) / 128, 2), 256, 0, stream>>>(
        zb, IN_DIM, 0L,
        WsbT, IN_DIM, (long)HD * IN_DIM,
        bias_cat, (long)HD, nullptr, nullptr,
        fs, HD, (long)N * HD,
        N, IN_DIM);

    // Edge scores + z-space aggregation
    if (fused) {
        score_agg_kernel<<<N, 256, 0, stream>>>(fs, fd, zb, rowptr, csr_src, atn16, agg, N);
    } else {
        score_csr_kernel<<<2500, 256, 0, stream>>>(fs, fd, rowptr, csr_src, atn16, expbuf, denomB, N);
        agg_z_kernel<<<2500, 256, 0, stream>>>(zb, rowptr, csr_src, expbuf, denomB, agg, N);
    }

    // out = lrelu(agg @ Wfinal^T + cvec + deg?bsW_tot), fused epilogue
    mfma_gemm_kernel<1><<<dim3(OUTD / 128, (N + 127) / 128, 1), 256, 0, stream>>>(
        agg, H_HEADS * IN_DIM, 0L,
        Wfinal, H_HEADS * IN_DIM, 0L,
        cvec, 0L, bsW_tot, rowptr,
        out, OUTD, 0L,
        N, H_HEADS * IN_DIM);
}

// Round 4
// 357.751 us; speedup vs baseline: 1.1399x; 1.0222x over previous
//
#include <hip/hip_runtime.h>
#include <hip/hip_bf16.h>
#include <math.h>

#define H_HEADS 4
#define D_HEAD 512
#define HD 2048
#define IN_DIM 256
#define OUTD 512
#define NEG 0.2f

typedef __hip_bfloat16 bf16;
typedef _Float16 f16;
typedef __attribute__((ext_vector_type(2))) _Float16 h2v;  // packed fp16 pair
typedef __attribute__((ext_vector_type(8))) short s16x8;   // 8 x bf16 (4 VGPRs)
typedef __attribute__((ext_vector_type(4))) float f32x4;   // MFMA accumulator

__device__ __forceinline__ float bflo(unsigned w) { union { unsigned u; float f; } x; x.u = w << 16; return x.f; }
__device__ __forceinline__ float bfhi(unsigned w) { union { unsigned u; float f; } x; x.u = w & 0xffff0000u; return x.f; }

// ---------------- batched MFMA bf16 GEMM ----------------
// C_z[row, col] = sum_k A_z[row, k] * Bt_z[col, k]
// MODE 0: bf16 output, + bias[col].
// MODE 1: fp32 output, fused: lrelu(acc + bias[col] + (deg(row)>0 ? bias2[col] : 0)).
// MODE 2: f16 output, + bias[col].
// Tile 128x128, BK=32; staging rows clamped to M-1 (never stored OOB).
// LDS bank-conflict fix: chunk index XOR-swizzled by (row>>1)&3 on both the
// staging global-source side and the fragment-read side.
// K-loop is 2-PHASE DOUBLE-BUFFERED: STAGE of tile t+1 issued BEFORE the
// ds_read+MFMA of tile t, so the vmcnt(0) drain at the end-of-iter barrier
// lands after the compute phase instead of before it.
// 16-bit epilogue is SINGLE-PHASE: all 4 waves write their 64x64 quadrant into
// a full 128x136 LDS buffer, one barrier, then 8 coalesced store iterations.
template<int MODE>
__global__ __launch_bounds__(256)
void mfma_gemm_kernel(const bf16* __restrict__ A, int lda, long aOff,
                      const bf16* __restrict__ Bt, int ldb, long bOff,
                      const float* __restrict__ bias, long biasOff,
                      const float* __restrict__ bias2, const int* __restrict__ rowptr,
                      void* __restrict__ Cv, int ldc, long cOff,
                      int M, int K)
{
    constexpr int SMEM_BYTES = (MODE == 1) ? (64 * 132 * 4) : (128 * 136 * 2);
    static_assert(SMEM_BYTES >= 4 * 4096 * 2, "staging dbuf must fit");
    __shared__ __align__(16) char smem_raw[SMEM_BYTES];
    bf16* stg = (bf16*)smem_raw;   // [2][A:4096 | B:4096] elements

    const int tid  = threadIdx.x;
    const int r0   = blockIdx.y * 128;
    const int n0   = blockIdx.x * 128;
    const int z    = blockIdx.z;
    const int lane = tid & 63;
    const int wave = tid >> 6;
    const int wr   = (wave >> 1) * 64;
    const int wc   = (wave & 1) * 64;
    const int l15  = lane & 15;
    const int quad = lane >> 4;

    const bf16* Az = A + aOff * (long)z;
    const bf16* Bz = Bt + bOff * (long)z;

    f32x4 acc[4][4];
    #pragma unroll
    for (int i = 0; i < 4; i++)
        #pragma unroll
        for (int j = 0; j < 4; j++)
            #pragma unroll
            for (int r = 0; r < 4; r++) acc[i][j][r] = 0.f;

    const int srow = tid >> 2;
    // XOR-swizzle: this lane fetches global chunk (k8 ^ key(row)); same 64B window.
    const int skof = (((tid & 3) ^ ((srow >> 1) & 3)) * 8);
    const int swz  = (l15 >> 1) & 3;   // reader-side key: row&15 == l15

    auto stage_tile = [&](int c, int k0) {
        bf16* As = stg + c * 8192;
        bf16* Bs = As + 4096;
        #pragma unroll
        for (int p = 0; p < 2; p++) {
            int ar = r0 + p * 64 + srow;
            if (ar >= M) ar = M - 1;
            const bf16* ga = Az + (size_t)ar * lda + k0 + skof;
            __builtin_amdgcn_global_load_lds(
                (const __attribute__((address_space(1))) void*)ga,
                (__attribute__((address_space(3))) void*)(As + (p * 256 + tid) * 8),
                16, 0, 0);
            const bf16* gb = Bz + (size_t)(n0 + p * 64 + srow) * ldb + k0 + skof;
            __builtin_amdgcn_global_load_lds(
                (const __attribute__((address_space(1))) void*)gb,
                (__attribute__((address_space(3))) void*)(Bs + (p * 256 + tid) * 8),
                16, 0, 0);
        }
    };

    stage_tile(0, 0);
    __syncthreads();               // buf0 resident
    int cbuf = 0;
    for (int k0 = 0; k0 < K; k0 += 32) {
        if (k0 + 32 < K) stage_tile(cbuf ^ 1, k0 + 32);   // prefetch next tile

        const bf16* As = stg + cbuf * 8192;
        const bf16* Bs = As + 4096;
        s16x8 af[4], bg[4];
        #pragma unroll
        for (int i = 0; i < 4; i++)
            af[i] = *(const s16x8*)(As + (wr + i * 16 + l15) * 32 + (quad ^ swz) * 8);
        #pragma unroll
        for (int j = 0; j < 4; j++)
            bg[j] = *(const s16x8*)(Bs + (wc + j * 16 + l15) * 32 + (quad ^ swz) * 8);
        #pragma unroll
        for (int i = 0; i < 4; i++)
            #pragma unroll
            for (int j = 0; j < 4; j++)
                acc[i][j] = __builtin_amdgcn_mfma_f32_16x16x32_bf16(af[i], bg[j], acc[i][j], 0, 0, 0);
        __syncthreads();           // drains prefetch (post-compute) + guards buf reuse
        cbuf ^= 1;
    }

    // C/D frag layout: col = lane&15, row = quad*4 + reg (m89/m91 verified)
    if (MODE == 0 || MODE == 2) {
        float bv[4];
        #pragma unroll
        for (int j = 0; j < 4; j++)
            bv[j] = bias ? bias[biasOff * (long)z + n0 + wc + j * 16 + l15] : 0.f;

        const long cb = cOff * (long)z;

        // single-phase transpose: every wave writes its own quadrant
        if (MODE == 0) {
            bf16* Cs = (bf16*)smem_raw;
            #pragma unroll
            for (int i = 0; i < 4; i++)
                #pragma unroll
                for (int j = 0; j < 4; j++)
                    #pragma unroll
                    for (int r = 0; r < 4; r++)
                        Cs[(wr + i * 16 + quad * 4 + r) * 136 + wc + j * 16 + l15] =
                            __float2bfloat16(acc[i][j][r] + bv[j]);
        } else {
            f16* Cs = (f16*)smem_raw;
            #pragma unroll
            for (int i = 0; i < 4; i++)
                #pragma unroll
                for (int j = 0; j < 4; j++)
                    #pragma unroll
                    for (int r = 0; r < 4; r++)
                        Cs[(wr + i * 16 + quad * 4 + r) * 136 + wc + j * 16 + l15] =
                            (f16)(acc[i][j][r] + bv[j]);
        }
        __syncthreads();
        #pragma unroll
        for (int it = 0; it < 8; it++) {
            const int idx  = it * 256 + tid;
            const int lrow = idx >> 4;
            const int lcol = (idx & 15) * 8;
            const int grow = r0 + lrow;
            if (grow < M)
                *(uint4*)((short*)Cv + cb + (size_t)grow * ldc + n0 + lcol) =
                    *(const uint4*)((const short*)smem_raw + lrow * 136 + lcol);
        }
    } else {
        float* C = (float*)Cv;
        float* Csf = (float*)smem_raw;     // 64 x 132 (padded)

        #pragma unroll
        for (int p = 0; p < 2; p++) {
            __syncthreads();
            if (wr == p * 64) {
                #pragma unroll
                for (int i = 0; i < 4; i++)
                    #pragma unroll
                    for (int j = 0; j < 4; j++)
                        #pragma unroll
                        for (int r = 0; r < 4; r++)
                            Csf[(i * 16 + quad * 4 + r) * 132 + wc + j * 16 + l15] = acc[i][j][r];
            }
            __syncthreads();
            #pragma unroll
            for (int it = 0; it < 8; it++) {
                const int idx  = it * 256 + tid;
                const int lrow = idx >> 5;
                const int lcol = (idx & 31) * 4;
                const int grow = r0 + p * 64 + lrow;
                if (grow < M) {
                    const int gcol = n0 + lcol;
                    float4 v  = *(const float4*)(Csf + lrow * 132 + lcol);
                    const float4 c4 = *(const float4*)(bias + gcol);
                    const float4 b4 = *(const float4*)(bias2 + gcol);
                    const bool has = rowptr[grow + 1] > rowptr[grow];
                    v.x += c4.x + (has ? b4.x : 0.f);
                    v.y += c4.y + (has ? b4.y : 0.f);
                    v.z += c4.z + (has ? b4.z : 0.f);
                    v.w += c4.w + (has ? b4.w : 0.f);
                    v.x = v.x > 0.f ? v.x : NEG * v.x;
                    v.y = v.y > 0.f ? v.y : NEG * v.y;
                    v.z = v.z > 0.f ? v.z : NEG * v.z;
                    v.w = v.w > 0.f ? v.w : NEG * v.w;
                    *(float4*)(C + (size_t)grow * ldc + gcol) = v;
                }
            }
        }
    }
}

// ---------------- prep: casts / transposes / bias concat / attn-f16 / cnt-zero
// plus (extra block range) the two 2048-dot reductions (cvec / bsW_tot).
__global__ __launch_bounds__(256)
void prep_kernel(const float* __restrict__ W_src, const float* __restrict__ W_dst,
                 const float* __restrict__ W_fc, const float* __restrict__ b_src,
                 const float* __restrict__ b_dst, const float* __restrict__ attn,
                 const float* __restrict__ b_fc, const float* __restrict__ gat_bias,
                 bf16* __restrict__ WsbT, bf16* __restrict__ WdbT,
                 bf16* __restrict__ WfcT, bf16* __restrict__ Wsb,
                 float* __restrict__ bias_cat, f16* __restrict__ atn16,
                 int* __restrict__ cnt, int nCnt,
                 float* __restrict__ cvec, float* __restrict__ bsW_tot, int prepBlocks)
{
    __shared__ float red[256];
    if ((int)blockIdx.x >= prepBlocks) {
        // reduction role: cvec[j] = gat_bias @ W_fc[:,j] + b_fc[j]  (b < OUTD)
        //                 bsW_tot[j] = b_src @ W_fc[:,j]            (b >= OUTD)
        const int b = blockIdx.x - prepBlocks;
        const int t = threadIdx.x;
        const bool isCvec = b < OUTD;
        const int j = isCvec ? b : b - OUTD;
        const float* vec = isCvec ? gat_bias : b_src;
        float s = 0.f;
        for (int k = t; k < HD; k += 256)
            s = fmaf(vec[k], W_fc[(size_t)k * OUTD + j], s);
        red[t] = s;
        __syncthreads();
        for (int o = 128; o > 0; o >>= 1) {
            if (t < o) red[t] += red[t + o];
            __syncthreads();
        }
        if (t == 0) {
            if (isCvec) cvec[j] = red[0] + b_fc[j];
            else bsW_tot[j] = red[0];
        }
        return;
    }
    int idx = blockIdx.x * 256 + threadIdx.x;
    if (idx < 524288) {
        const int n = idx >> 8, k = idx & 255;
        WsbT[idx] = __float2bfloat16(W_src[(size_t)k * HD + n]);
        return;
    }
    idx -= 524288;
    if (idx < 524288) {
        const int n = idx >> 8, k = idx & 255;
        WdbT[idx] = __float2bfloat16(W_dst[(size_t)k * HD + n]);
        return;
    }
    idx -= 524288;
    if (idx < 1048576) {
        const int n = idx >> 9, t = idx & 511;      // n = h*512 + j
        const int h = n >> 9, j = n & 511;
        WfcT[idx] = __float2bfloat16(W_fc[(size_t)(h * 512 + t) * OUTD + j]);
        return;
    }
    idx -= 1048576;
    if (idx < 524288) {
        Wsb[idx] = __float2bfloat16(W_src[idx]);
        return;
    }
    idx -= 524288;
    if (idx < 2 * HD) {
        bias_cat[idx] = (idx < HD) ? b_src[idx] : b_dst[idx - HD];
        return;
    }
    idx -= 2 * HD;
    if (idx < HD) {
        atn16[idx] = (f16)attn[idx];
        return;
    }
    idx -= HD;
    if (idx < nCnt) cnt[idx] = 0;
}

// cast z -> bf16, plus (tail range) degree histogram (cnt zeroed by prep)
__global__ void cast_hist_kernel(const float* __restrict__ S, bf16* __restrict__ T,
                                 long n4, const int* __restrict__ dst,
                                 int* __restrict__ cnt, int E)
{
    long t = (long)blockIdx.x * 256 + threadIdx.x;
    if (t < n4) {
        const long i = t * 4;
        const float4 v = *(const float4*)(S + i);
        T[i + 0] = __float2bfloat16(v.x);
        T[i + 1] = __float2bfloat16(v.y);
        T[i + 2] = __float2bfloat16(v.z);
        T[i + 3] = __float2bfloat16(v.w);
        return;
    }
    t -= n4;
    if (t < E) atomicAdd(&cnt[dst[t]], 1);
}

// single-workgroup scan, shfl-based wave scans; emits cursor[] (= rowptr) too.
__global__ __launch_bounds__(1024)
void scan_kernel(const int* __restrict__ cnt, int* __restrict__ rowptr,
                 int* __restrict__ cursor, int n)
{
    __shared__ int wsum[16];
    __shared__ int carry_s;
    const int tid  = threadIdx.x;
    const int lane = tid & 63;
    const int wv   = tid >> 6;
    if (tid == 0) { carry_s = 0; rowptr[0] = 0; cursor[0] = 0; }
    __syncthreads();
    for (int base = 0; base < n; base += 1024) {
        const int i = base + tid;
        int v = (i < n) ? cnt[i] : 0;
        #pragma unroll
        for (int d = 1; d < 64; d <<= 1) {
            const int t = __shfl_up(v, d, 64);
            if (lane >= d) v += t;
        }
        if (lane == 63) wsum[wv] = v;
        __syncthreads();
        if (tid < 16) {
            int w = wsum[tid];
            #pragma unroll
            for (int d = 1; d < 16; d <<= 1) {
                const int t = __shfl_up(w, d, 64);
                if (tid >= d) w += t;
            }
            wsum[tid] = w;
        }
        __syncthreads();
        const int incl = v + (wv ? wsum[wv - 1] : 0) + carry_s;
        if (i < n) {
            rowptr[i + 1] = incl;
            if (i + 1 < n) cursor[i + 1] = incl;
        }
        __syncthreads();                 // all reads of carry_s / wsum done
        if (tid == 1023) carry_s += wsum[15];
        __syncthreads();                 // carry_s/wsum safe for next chunk
    }
}

__global__ void scatter_kernel(const int* __restrict__ src, const int* __restrict__ dst,
                               int* __restrict__ cursor, int* __restrict__ csr_src, int E)
{
    const int e = blockIdx.x * 256 + threadIdx.x;
    if (e >= E) return;
    const int pos = atomicAdd(&cursor[dst[e]], 1);
    csr_src[pos] = src[e];
}

// ---------------- edge scores: packed-f16 math ----------------
// LeakyReLU(s, 0.2) == 0.6*s + 0.4*|s|, branch-free; |s| via sign-bit mask on
// the packed word. All ops compile to v_pk_{add,mul,fma}_f16.
__device__ __forceinline__ float score_head_h2(const uint4 pa, const uint4 pb, const uint4 at)
{
    const unsigned* ua = (const unsigned*)&pa;
    const unsigned* ub = (const unsigned*)&pb;
    const unsigned* ut = (const unsigned*)&at;
    h2v acc = (h2v)(_Float16)0.f;
    const h2v c06 = (h2v)(_Float16)0.6f;
    const h2v c04 = (h2v)(_Float16)0.4f;
    #pragma unroll
    for (int c = 0; c < 4; c++) {
        union { unsigned u; h2v h; } A, B, T, S, Ab;
        A.u = ua[c]; B.u = ub[c]; T.u = ut[c];
        S.h = A.h + B.h;
        Ab.u = S.u & 0x7fff7fffu;
        const h2v l = S.h * c06 + Ab.h * c04;
        acc += l * T.h;
    }
    return (float)acc.x + (float)acc.y;
}

// ---------------- FUSED score + z-space aggregation, per-(node,head) ----------------
// block = node, wave = head. Edge list staged once into LDS (shared by the 4
// head-waves; removes the per-iter csr_src cache load from the gather's
// dependent chain -> uniform ~60cy LDS broadcast instead). 4-edge unroll:
// 4 fs gathers + 4 zb gathers in flight, 4 interleaved shuffle-reduce chains.
// Tail edges handled by index-clamp (duplicate gather, harmless) + zeroed exp.
// agg[v, h*256+k] = (sum_e exp(s_eh) * zb[u_e, k]) / (sum_e exp(s_eh))
__global__ __launch_bounds__(256)
void score_agg_kernel(const f16* __restrict__ fs, const f16* __restrict__ fd,
                      const bf16* __restrict__ zb,
                      const int* __restrict__ rowptr, const int* __restrict__ csr_src,
                      const f16* __restrict__ atn16, bf16* __restrict__ agg, int N)
{
    __shared__ int uls[256];
    const int h    = threadIdx.x >> 6;     // wave index = head
    const int lane = threadIdx.x & 63;
    const int v    = blockIdx.x;
    if (v >= N) return;

    const uint4 at = *(const uint4*)(atn16 + h * D_HEAD + lane * 8);
    const f16* fsh = fs + h * D_HEAD + (size_t)lane * 8;

    const int off0 = rowptr[v], off1 = rowptr[v + 1];
    const int deg  = off1 - off0;
    float acc[4] = {0.f, 0.f, 0.f, 0.f};
    float den = 0.f;

    const uint4 fdr = *(const uint4*)(fd + (size_t)v * HD + h * D_HEAD + lane * 8);

    for (int base = 0; base < deg; base += 256) {      // single pass for deg<=256
        const int nb = (deg - base) < 256 ? (deg - base) : 256;
        __syncthreads();                                // guard uls reuse
        for (int t = threadIdx.x; t < nb; t += 256)
            uls[t] = csr_src[off0 + base + t];
        __syncthreads();

        for (int e = 0; e < nb; e += 4) {
            const int i1 = (e + 1 < nb) ? e + 1 : e;
            const int i2 = (e + 2 < nb) ? e + 2 : e;
            const int i3 = (e + 3 < nb) ? e + 3 : e;
            const int u0 = uls[e], u1 = uls[i1], u2 = uls[i2], u3 = uls[i3];
            const uint4 pa0 = *(const uint4*)(fsh + (size_t)u0 * HD);
            const uint4 pa1 = *(const uint4*)(fsh + (size_t)u1 * HD);
            const uint4 pa2 = *(const uint4*)(fsh + (size_t)u2 * HD);
            const uint4 pa3 = *(const uint4*)(fsh + (size_t)u3 * HD);
            const uint2 z0 = *(const uint2*)(zb + (size_t)u0 * IN_DIM + lane * 4);
            const uint2 z1 = *(const uint2*)(zb + (size_t)u1 * IN_DIM + lane * 4);
            const uint2 z2 = *(const uint2*)(zb + (size_t)u2 * IN_DIM + lane * 4);
            const uint2 z3 = *(const uint2*)(zb + (size_t)u3 * IN_DIM + lane * 4);

            float s0 = score_head_h2(pa0, fdr, at);
            float s1 = score_head_h2(pa1, fdr, at);
            float s2 = score_head_h2(pa2, fdr, at);
            float s3 = score_head_h2(pa3, fdr, at);
            #pragma unroll
            for (int ofs = 32; ofs > 0; ofs >>= 1) {
                s0 += __shfl_xor(s0, ofs, 64);
                s1 += __shfl_xor(s1, ofs, 64);
                s2 += __shfl_xor(s2, ofs, 64);
                s3 += __shfl_xor(s3, ofs, 64);
            }
            // scores O(0.2): max-subtraction safely skipped (cancels in
            // num/den anyway, so deferred normalization is exact)
            const float e0 = __expf(s0);
            const float e1 = (e + 1 < nb) ? __expf(s1) : 0.f;
            const float e2 = (e + 2 < nb) ? __expf(s2) : 0.f;
            const float e3 = (e + 3 < nb) ? __expf(s3) : 0.f;
            den += e0 + e1 + e2 + e3;
            const float zc0[4] = {bflo(z0.x), bfhi(z0.x), bflo(z0.y), bfhi(z0.y)};
            const float zc1[4] = {bflo(z1.x), bfhi(z1.x), bflo(z1.y), bfhi(z1.y)};
            const float zc2[4] = {bflo(z2.x), bfhi(z2.x), bflo(z2.y), bfhi(z2.y)};
            const float zc3[4] = {bflo(z3.x), bfhi(z3.x), bflo(z3.y), bfhi(z3.y)};
            #pragma unroll
            for (int c = 0; c < 4; c++)
                acc[c] += (e0 * zc0[c] + e1 * zc1[c]) + (e2 * zc2[c] + e3 * zc3[c]);
        }
    }
    if (deg > 0) {
        const float inv = 1.f / den;
        #pragma unroll
        for (int c = 0; c < 4; c++) acc[c] *= inv;
    }

    union { uint2 u; short s[4]; } pk;
    #pragma unroll
    for (int c = 0; c < 4; c++) {
        const bf16 b = __float2bfloat16(acc[c]);
        pk.s[c] = *(const short*)&b;
    }
    *(uint2*)(agg + (size_t)v * (H_HEADS * IN_DIM) + h * IN_DIM + lane * 4) = pk.u;
}

// ---------------- fallback pair (used only if workspace too small for a
// separate agg buffer; agg then overlays fs, so score/agg must be 2 passes)
__global__ __launch_bounds__(256)
void score_csr_kernel(const f16* __restrict__ fs, const f16* __restrict__ fd,
                      const int* __restrict__ rowptr, const int* __restrict__ csr_src,
                      const f16* __restrict__ atn16, float* __restrict__ expbuf,
                      float* __restrict__ denomB, int N)
{
    const int wave = threadIdx.x >> 6;
    const int lane = threadIdx.x & 63;
    const int wgid = blockIdx.x * 4 + wave;
    const int nw   = gridDim.x * 4;

    uint4 at[H_HEADS];
    #pragma unroll
    for (int h = 0; h < H_HEADS; h++)
        at[h] = *(const uint4*)(atn16 + h * D_HEAD + lane * 8);

    for (int v = wgid; v < N; v += nw) {
        const int off0 = rowptr[v], off1 = rowptr[v + 1];
        if (off0 == off1) continue;
        uint4 fdr[H_HEADS];
        #pragma unroll
        for (int h = 0; h < H_HEADS; h++)
            fdr[h] = *(const uint4*)(fd + (size_t)v * HD + h * D_HEAD + lane * 8);

        float4 den = make_float4(0.f, 0.f, 0.f, 0.f);
        for (int o = off0; o < off1; o += 2) {
            const bool two = (o + 1 < off1);
            const int u0 = csr_src[o];
            const int u1 = two ? csr_src[o + 1] : u0;
            const f16* f0 = fs + (size_t)u0 * HD + lane * 8;
            const f16* f1 = fs + (size_t)u1 * HD + lane * 8;
            uint4 pa0[H_HEADS], pa1[H_HEADS];
            #pragma unroll
            for (int h = 0; h < H_HEADS; h++) pa0[h] = *(const uint4*)(f0 + h * D_HEAD);
            #pragma unroll
            for (int h = 0; h < H_HEADS; h++) pa1[h] = *(const uint4*)(f1 + h * D_HEAD);

            float s0[H_HEADS], s1[H_HEADS];
            #pragma unroll
            for (int h = 0; h < H_HEADS; h++) {
                s0[h] = score_head_h2(pa0[h], fdr[h], at[h]);
                s1[h] = score_head_h2(pa1[h], fdr[h], at[h]);
            }
            #pragma unroll
            for (int ofs = 32; ofs > 0; ofs >>= 1) {
                #pragma unroll
                for (int h = 0; h < H_HEADS; h++) {
                    s0[h] += __shfl_xor(s0[h], ofs, 64);
                    s1[h] += __shfl_xor(s1[h], ofs, 64);
                }
            }
            const float4 e0 = make_float4(expf(s0[0]), expf(s0[1]), expf(s0[2]), expf(s0[3]));
            den.x += e0.x; den.y += e0.y; den.z += e0.z; den.w += e0.w;
            float4 e1;
            if (two) {
                e1 = make_float4(expf(s1[0]), expf(s1[1]), expf(s1[2]), expf(s1[3]));
                den.x += e1.x; den.y += e1.y; den.z += e1.z; den.w += e1.w;
            }
            if (lane == 0) {
                *(float4*)(expbuf + (size_t)o * H_HEADS) = e0;
                if (two) *(float4*)(expbuf + (size_t)(o + 1) * H_HEADS) = e1;
            }
        }
        if (lane == 0) *(float4*)(denomB + (size_t)v * H_HEADS) = den;
    }
}

__global__ __launch_bounds__(256)
void agg_z_kernel(const bf16* __restrict__ zb, const int* __restrict__ rowptr,
                  const int* __restrict__ csr_src, const float* __restrict__ expbuf,
                  const float* __restrict__ denomB, bf16* __restrict__ agg, int N)
{
    const int wave = threadIdx.x >> 6;
    const int lane = threadIdx.x & 63;
    const int wgid = blockIdx.x * 4 + wave;
    const int nw   = gridDim.x * 4;

    for (int v = wgid; v < N; v += nw) {
        const int off0 = rowptr[v], off1 = rowptr[v + 1];
        float acc[H_HEADS][4];
        #pragma unroll
        for (int h = 0; h < H_HEADS; h++)
            #pragma unroll
            for (int c = 0; c < 4; c++) acc[h][c] = 0.f;

        if (off1 > off0) {
            const float4 den = *(const float4*)(denomB + (size_t)v * H_HEADS);
            const float4 inv = make_float4(1.f / den.x, 1.f / den.y, 1.f / den.z, 1.f / den.w);
            int o = off0;
            for (; o + 1 < off1; o += 2) {
                const float4 e0 = *(const float4*)(expbuf + (size_t)o * H_HEADS);
                const float4 e1 = *(const float4*)(expbuf + (size_t)(o + 1) * H_HEADS);
                const int u0 = csr_src[o], u1 = csr_src[o + 1];
                const uint2 z0 = *(const uint2*)(zb + (size_t)u0 * IN_DIM + lane * 4);
                const uint2 z1 = *(const uint2*)(zb + (size_t)u1 * IN_DIM + lane * 4);
                const float a0[4] = {e0.x * inv.x, e0.y * inv.y, e0.z * inv.z, e0.w * inv.w};
                const float a1[4] = {e1.x * inv.x, e1.y * inv.y, e1.z * inv.z, e1.w * inv.w};
                const float zc0[4] = {bflo(z0.x), bfhi(z0.x), bflo(z0.y), bfhi(z0.y)};
                const float zc1[4] = {bflo(z1.x), bfhi(z1.x), bflo(z1.y), bfhi(z1.y)};
                #pragma unroll
                for (int h = 0; h < H_HEADS; h++)
                    #pragma unroll
                    for (int c = 0; c < 4; c++)
                        acc[h][c] += a0[h] * zc0[c] + a1[h] * zc1[c];
            }
            if (o < off1) {
                const float4 e0 = *(const float4*)(expbuf + (size_t)o * H_HEADS);
                const int u0 = csr_src[o];
                const uint2 z0 = *(const uint2*)(zb + (size_t)u0 * IN_DIM + lane * 4);
                const float a0[4] = {e0.x * inv.x, e0.y * inv.y, e0.z * inv.z, e0.w * inv.w};
                const float zc0[4] = {bflo(z0.x), bfhi(z0.x), bflo(z0.y), bfhi(z0.y)};
                #pragma unroll
                for (int h = 0; h < H_HEADS; h++)
                    #pragma unroll
                    for (int c = 0; c < 4; c++)
                        acc[h][c] += a0[h] * zc0[c];
            }
        }
        #pragma unroll
        for (int h = 0; h < H_HEADS; h++) {
            union { uint2 u; short s[4]; } pk;
            #pragma unroll
            for (int c = 0; c < 4; c++) {
                const bf16 b = __float2bfloat16(acc[h][c]);
                pk.s[c] = *(const short*)&b;
            }
            *(uint2*)(agg + (size_t)v * (H_HEADS * IN_DIM) + h * IN_DIM + lane * 4) = pk.u;
        }
    }
}

extern "C" void kernel_launch(void* const* d_in, const int* in_sizes, int n_in,
                              void* d_out, int out_size, void* d_ws, size_t ws_size,
                              hipStream_t stream)
{
    const float* z        = (const float*)d_in[0];
    const int*   src      = (const int*)d_in[1];
    const int*   dst      = (const int*)d_in[2];
    const float* W_src    = (const float*)d_in[3];
    const float* b_src    = (const float*)d_in[4];
    const float* W_dst    = (const float*)d_in[5];
    const float* b_dst    = (const float*)d_in[6];
    const float* attn     = (const float*)d_in[7];
    const float* gat_bias = (const float*)d_in[8];
    const float* W_fc     = (const float*)d_in[9];
    const float* b_fc     = (const float*)d_in[10];
    float* out = (float*)d_out;

    const int N = in_sizes[0] / IN_DIM;   // 20000
    const int E = in_sizes[1];            // 100000

    // Workspace (~184 MB base; +41 MB for separate agg if ws_size allows).
    char* p = (char*)d_ws;
    const size_t featB = (size_t)N * HD * 2;
    f16* fs       = (f16*)p;   p += featB;                               // 81.92 MB (f16)
    f16* fd       = (f16*)p;   p += featB;                               // 81.92 MB (f16)
    bf16* zb      = (bf16*)p;  p += (size_t)N * IN_DIM * sizeof(bf16);   // 10.24 MB
    bf16* WsbT    = (bf16*)p;  p += (size_t)HD * IN_DIM * sizeof(bf16);  // 1.05 MB
    bf16* WdbT    = (bf16*)p;  p += (size_t)HD * IN_DIM * sizeof(bf16);  // 1.05 MB
    bf16* Wsb     = (bf16*)p;  p += (size_t)IN_DIM * HD * sizeof(bf16);  // 1.05 MB
    bf16* WfcT    = (bf16*)p;  p += (size_t)HD * D_HEAD * sizeof(bf16);  // 2.10 MB
    bf16* Wfinal  = (bf16*)p;  p += (size_t)OUTD * 1024 * sizeof(bf16);  // 1.05 MB
    float* bias_cat = (float*)p; p += (size_t)2 * HD * sizeof(float);    // 16 KB
    f16* atn16    = (f16*)p;   p += (size_t)HD * sizeof(f16);            // 4 KB
    float* bsW_tot = (float*)p; p += (size_t)OUTD * sizeof(float);
    float* cvec   = (float*)p; p += (size_t)OUTD * sizeof(float);
    float* expbuf = (float*)p; p += (size_t)E * H_HEADS * sizeof(float); // 1.6 MB
    float* denomB = (float*)p; p += (size_t)N * H_HEADS * sizeof(float); // 0.32 MB
    int* cnt      = (int*)p;   p += ((size_t)N * 4 + 15) & ~15ULL;
    int* rowptr   = (int*)p;   p += ((size_t)(N + 1) * 4 + 15) & ~15ULL;
    int* cursor   = (int*)p;   p += ((size_t)N * 4 + 15) & ~15ULL;
    int* csr_src  = (int*)p;   p += ((size_t)E * 4 + 15) & ~15ULL;

    // Separate agg buffer (fused score+agg needs fs live while writing agg);
    // fall back to overlaying fs + 2-pass kernels if workspace is too small.
    bf16* aggSep = (bf16*)p;
    const size_t needFused = (size_t)(p - (char*)d_ws) + (size_t)N * (H_HEADS * IN_DIM) * sizeof(bf16);
    const bool fused = (ws_size >= needFused);
    bf16* agg = fused ? aggSep : (bf16*)fs;

    // Prep: weight casts/transposes + bias concat + attn f16 + cnt zero,
    // plus cvec/bsW_tot reductions in an extra block range.
    const int prepElems  = 524288 * 3 + 1048576 + 2 * HD + HD + N;
    const int prepBlocks = (prepElems + 255) / 256;
    prep_kernel<<<prepBlocks + 2 * OUTD, 256, 0, stream>>>(
        W_src, W_dst, W_fc, b_src, b_dst, attn, b_fc, gat_bias,
        WsbT, WdbT, WfcT, Wsb, bias_cat, atn16, cnt, N, cvec, bsW_tot, prepBlocks);

    // z cast + degree histogram (one launch)
    const long n4 = (long)N * IN_DIM / 4;
    cast_hist_kernel<<<(int)((n4 + E + 255) / 256), 256, 0, stream>>>(z, zb, n4, dst, cnt, E);

    // CSR build (scan also emits cursor)
    scan_kernel<<<1, 1024, 0, stream>>>(cnt, rowptr, cursor, N);
    scatter_kernel<<<(E + 255) / 256, 256, 0, stream>>>(src, dst, cursor, csr_src, E);

    // Wfinal[j, h*256+k] = Wcomb_h[k, j]
    mfma_gemm_kernel<0><<<dim3(IN_DIM / 128, D_HEAD / 128, H_HEADS), 256, 0, stream>>>(
        WfcT, D_HEAD, (long)D_HEAD * D_HEAD,
        Wsb, HD, (long)D_HEAD,
        nullptr, 0, nullptr, nullptr,
        Wfinal, 1024, (long)IN_DIM,
        D_HEAD, D_HEAD);

    // fs,fd = zb @ {W_src,W_dst} + {b_src,b_dst}, f16 output (one z=2 dispatch)
    mfma_gemm_kernel<2><<<dim3(HD / 128, (N + 127) / 128, 2), 256, 0, stream>>>(
        zb, IN_DIM, 0L,
        WsbT, IN_DIM, (long)HD * IN_DIM,
        bias_cat, (long)HD, nullptr, nullptr,
        fs, HD, (long)N * HD,
        N, IN_DIM);

    // Edge scores + z-space aggregation
    if (fused) {
        score_agg_kernel<<<N, 256, 0, stream>>>(fs, fd, zb, rowptr, csr_src, atn16, agg, N);
    } else {
        score_csr_kernel<<<2500, 256, 0, stream>>>(fs, fd, rowptr, csr_src, atn16, expbuf, denomB, N);
        agg_z_kernel<<<2500, 256, 0, stream>>>(zb, rowptr, csr_src, expbuf, denomB, agg, N);
    }

    // out = lrelu(agg @ Wfinal^T + cvec + deg?bsW_tot), fused epilogue
    mfma_gemm_kernel<1><<<dim3(OUTD / 128, (N + 127) / 128, 1), 256, 0, stream>>>(
        agg, H_HEADS * IN_DIM, 0L,
        Wfinal, H_HEADS * IN_DIM, 0L,
        cvec, 0L, bsW_tot, rowptr,
        out, OUTD, 0L,
        N, H_HEADS * IN_DIM);
}